// Round 2
// baseline (1541.693 us; speedup 1.0000x reference)
//
#include <hip/hip_runtime.h>
#include <math.h>

typedef unsigned short u16;
typedef __attribute__((ext_vector_type(8))) short short8;
typedef __attribute__((ext_vector_type(4))) float f32x4;

#define B_ 4
#define N_ 4096
#define C_ 512
#define H_ 8
#define D_ 64
#define KD_ 256
#define FF_ 2048
#define L_ 2

__device__ __forceinline__ float bf2f(u16 x) {
  return __builtin_bit_cast(float, (unsigned int)x << 16);
}
__device__ __forceinline__ u16 f2bf(float f) {
  unsigned int t = __builtin_bit_cast(unsigned int, f);
  return (u16)((t + 0x7fffu + ((t >> 16) & 1u)) >> 16);
}

// ---------------- f32 -> bf16 convert, 4 elems/thread ----------------
__global__ __launch_bounds__(256) void cvt_kernel(const float* __restrict__ in,
                                                  u16* __restrict__ out, int n4) {
  int i = blockIdx.x * 256 + threadIdx.x;
  if (i >= n4) return;
  float4 v = reinterpret_cast<const float4*>(in)[i];
  ushort4 o;
  o.x = f2bf(v.x); o.y = f2bf(v.y); o.z = f2bf(v.z); o.w = f2bf(v.w);
  reinterpret_cast<ushort4*>(out)[i] = o;
}

// ---------------- generic NT MFMA GEMM ----------------
// C[m,j] = sum_k A[m,k]*B[j,k]  (A:[M,K] lda, B:[N,K] ldb, both bf16)
// z-batch with per-z strides (sA1/sB1/sC1). 4 waves (2x2), BK=64.
// EPI: 1 bf16 out *alpha | 2 bf16 gelu(v+bias[j]) | 3 bf16 +bias[j](nullable)
//      4 bf16 +bias[m] | 5 bf16 K/V transposed store to [B, H*D, N]
template <int BM, int BN, int EPI>
__global__ __launch_bounds__(256, 2) void gemm_nt(
    const u16* __restrict__ A, const u16* __restrict__ B, void* __restrict__ Cout,
    const float* __restrict__ bias, int K, int lda, int ldb, int ldc,
    long sA1, long sB1, long sC1, float alpha) {
  constexpr int BK = 64;
  constexpr int LDT = BK + 8;
  constexpr int WM = BM / 2, WN = BN / 2;
  constexpr int FM = WM / 16, FN = WN / 16;
  constexpr int CA = BM * 8 / 256, CB = BN * 8 / 256;

  __shared__ u16 As[BM * LDT];
  __shared__ u16 Bs[BN * LDT];

  int zh = blockIdx.z;
  A += (long)zh * sA1;
  B += (long)zh * sB1;
  long coff = (long)zh * sC1;

  int tid = threadIdx.x;
  int lane = tid & 63, wid = tid >> 6;
  int wr = wid >> 1, wc = wid & 1;
  int row0 = blockIdx.x * BM, col0 = blockIdx.y * BN;

  f32x4 acc[FM][FN] = {};

  for (int k0 = 0; k0 < K; k0 += BK) {
#pragma unroll
    for (int i = 0; i < CA; ++i) {
      int c = tid + i * 256;
      int r = c >> 3, cb = (c & 7) * 8;
      uint4 v = *reinterpret_cast<const uint4*>(A + (long)(row0 + r) * lda + k0 + cb);
      *reinterpret_cast<uint4*>(&As[r * LDT + cb]) = v;
    }
#pragma unroll
    for (int i = 0; i < CB; ++i) {
      int c = tid + i * 256;
      int r = c >> 3, cb = (c & 7) * 8;
      uint4 v = *reinterpret_cast<const uint4*>(B + (long)(col0 + r) * ldb + k0 + cb);
      *reinterpret_cast<uint4*>(&Bs[r * LDT + cb]) = v;
    }
    __syncthreads();

    int lr = lane & 15, lk = (lane >> 4) * 8;
#pragma unroll
    for (int kk = 0; kk < BK; kk += 32) {
      short8 af[FM], bfr[FN];
#pragma unroll
      for (int mi = 0; mi < FM; ++mi)
        af[mi] = *reinterpret_cast<const short8*>(&As[(wr * WM + mi * 16 + lr) * LDT + kk + lk]);
#pragma unroll
      for (int nj = 0; nj < FN; ++nj)
        bfr[nj] = *reinterpret_cast<const short8*>(&Bs[(wc * WN + nj * 16 + lr) * LDT + kk + lk]);
#pragma unroll
      for (int mi = 0; mi < FM; ++mi)
#pragma unroll
        for (int nj = 0; nj < FN; ++nj)
          acc[mi][nj] = __builtin_amdgcn_mfma_f32_16x16x32_bf16(af[mi], bfr[nj], acc[mi][nj], 0, 0, 0);
    }
    __syncthreads();
  }

  // epilogue: C/D layout col=lane&15, row=(lane>>4)*4+reg
  int lc = lane & 15, rb = (lane >> 4) * 4;
#pragma unroll
  for (int mi = 0; mi < FM; ++mi) {
#pragma unroll
    for (int nj = 0; nj < FN; ++nj) {
      int j = col0 + wc * WN + nj * 16 + lc;
      int m0 = row0 + wr * WM + mi * 16 + rb;
#pragma unroll
      for (int r = 0; r < 4; ++r) {
        int m = m0 + r;
        float v = acc[mi][nj][r];
        if constexpr (EPI == 1) {
          reinterpret_cast<u16*>(Cout)[coff + (long)m * ldc + j] = f2bf(v * alpha);
        } else if constexpr (EPI == 2) {
          float t = v + bias[j];
          float gl = 0.5f * t * (1.f + erff(t * 0.70710678118f));
          reinterpret_cast<u16*>(Cout)[coff + (long)m * ldc + j] = f2bf(gl);
        } else if constexpr (EPI == 3) {
          float bi = bias ? bias[j] : 0.f;
          reinterpret_cast<u16*>(Cout)[coff + (long)m * ldc + j] = f2bf(v + bi);
        } else if constexpr (EPI == 4) {
          reinterpret_cast<u16*>(Cout)[coff + (long)m * ldc + j] = f2bf(v + bias[m]);
        } else {  // 5: store to [B, H*D, N]; m = b*4096+n, j = h*64+d
          long a = ((long)(m >> 12) * (H_ * D_) + j) * N_ + (m & (N_ - 1));
          reinterpret_cast<u16*>(Cout)[a] = f2bf(v);
        }
      }
    }
  }
}

// ---------------- softmax over rows of 256 (bf16 in/out, in place) ----------------
__global__ __launch_bounds__(256) void softmax_kernel(u16* __restrict__ P) {
  long row = (long)blockIdx.x * 4 + (threadIdx.x >> 6);
  int lane = threadIdx.x & 63;
  u16* p = P + row * KD_ + lane * 4;
  ushort4 u = *reinterpret_cast<const ushort4*>(p);
  float v0 = bf2f(u.x), v1 = bf2f(u.y), v2 = bf2f(u.z), v3 = bf2f(u.w);
  float mx = fmaxf(fmaxf(v0, v1), fmaxf(v2, v3));
#pragma unroll
  for (int o = 1; o < 64; o <<= 1) mx = fmaxf(mx, __shfl_xor(mx, o));
  float e0 = __expf(v0 - mx), e1 = __expf(v1 - mx), e2 = __expf(v2 - mx), e3 = __expf(v3 - mx);
  float sm = e0 + e1 + e2 + e3;
#pragma unroll
  for (int o = 1; o < 64; o <<= 1) sm += __shfl_xor(sm, o);
  float inv = 1.f / sm;
  ushort4 w;
  w.x = f2bf(e0 * inv); w.y = f2bf(e1 * inv); w.z = f2bf(e2 * inv); w.w = f2bf(e3 * inv);
  *reinterpret_cast<ushort4*>(p) = w;
}

// ---------------- residual add + LayerNorm (row of 512) ----------------
// xin: f32 (input x or d_out), yin: bf16, xout: f32 (may alias xin), xbout: bf16 or null
__global__ __launch_bounds__(256) void add_ln_kernel(
    const float* __restrict__ xin, const u16* __restrict__ yin,
    const float* __restrict__ g, const float* __restrict__ bt,
    float* __restrict__ xout, u16* __restrict__ xbout) {
  int row = blockIdx.x * 4 + (threadIdx.x >> 6);
  int lane = threadIdx.x & 63;
  long base = (long)row * C_ + lane * 8;
  float4 a0 = *reinterpret_cast<const float4*>(xin + base);
  float4 a1 = *reinterpret_cast<const float4*>(xin + base + 4);
  ushort4 u0 = *reinterpret_cast<const ushort4*>(yin + base);
  ushort4 u1 = *reinterpret_cast<const ushort4*>(yin + base + 4);
  float s[8] = {a0.x + bf2f(u0.x), a0.y + bf2f(u0.y), a0.z + bf2f(u0.z), a0.w + bf2f(u0.w),
                a1.x + bf2f(u1.x), a1.y + bf2f(u1.y), a1.z + bf2f(u1.z), a1.w + bf2f(u1.w)};
  float sum = 0.f;
#pragma unroll
  for (int i = 0; i < 8; ++i) sum += s[i];
#pragma unroll
  for (int o = 1; o < 64; o <<= 1) sum += __shfl_xor(sum, o);
  float mean = sum * (1.f / C_);
  float var = 0.f;
#pragma unroll
  for (int i = 0; i < 8; ++i) { float d = s[i] - mean; var += d * d; }
#pragma unroll
  for (int o = 1; o < 64; o <<= 1) var += __shfl_xor(var, o);
  float inv = rsqrtf(var * (1.f / C_) + 1e-5f);
  int c0 = lane * 8;
#pragma unroll
  for (int i = 0; i < 8; ++i) {
    float o = (s[i] - mean) * inv * g[c0 + i] + bt[c0 + i];
    xout[base + i] = o;
    if (xbout) xbout[base + i] = f2bf(o);
  }
}

extern "C" void kernel_launch(void* const* d_in, const int* in_sizes, int n_in,
                              void* d_out, int out_size, void* d_ws, size_t ws_size,
                              hipStream_t stream) {
  const float* x    = (const float*)d_in[0];
  const float* Wq   = (const float*)d_in[1];
  const float* Wk   = (const float*)d_in[2];
  const float* Wv   = (const float*)d_in[3];
  const float* Wo   = (const float*)d_in[4];
  const float* bo   = (const float*)d_in[5];
  const float* ln1g = (const float*)d_in[6];
  const float* ln1b = (const float*)d_in[7];
  const float* W1   = (const float*)d_in[8];
  const float* b1   = (const float*)d_in[9];
  const float* W2   = (const float*)d_in[10];
  const float* b2   = (const float*)d_in[11];
  const float* ln2g = (const float*)d_in[12];
  const float* ln2b = (const float*)d_in[13];
  const float* Ew   = (const float*)d_in[14];
  const float* Eb   = (const float*)d_in[15];
  float* xc = (float*)d_out;  // running residual x (f32), in-place LN; final = output

  // workspace layout: ~80 MB total (write-before-read every call; no overflow)
  char* wsp = (char*)d_ws;
  size_t off = 0;
  auto alloc = [&](size_t bytes) -> void* {
    void* p = wsp + off;
    off = (off + bytes + 255) & ~(size_t)255;
    return p;
  };
  u16* xb  = (u16*)alloc(8388608UL * 2);  // x bf16 [B,N,C]
  u16* Qb  = (u16*)alloc(8388608UL * 2);  // Q [B,N,H*D]; attn-out aliases (per-b, after QK(b))
  u16* KVt = (u16*)alloc(8388608UL * 2);  // K^T then V^T [B,H*D,N]; later y (bf16 [B,N,C])
  u16* Kpb = (u16*)alloc(524288UL * 2);   // Kp [B,H,KD,D]
  u16* Vpb = (u16*)alloc(524288UL * 2);   // Vp [B,H,D,KD]
  u16* Pb  = (u16*)alloc(8388608UL * 2);  // P per-batch [H,N,KD] / h1 chunk [4096,FF]
  u16* wqb = (u16*)alloc(524288UL * 2);
  u16* wkb = (u16*)alloc(524288UL * 2);
  u16* wvb = (u16*)alloc(524288UL * 2);
  u16* wob = (u16*)alloc(524288UL * 2);
  u16* w1b = (u16*)alloc(2097152UL * 2);
  u16* w2b = (u16*)alloc(2097152UL * 2);
  u16* ewb = (u16*)alloc(1048576UL * 2);
  u16* Ob = Qb;   // attn output aliases Q
  u16* yb = KVt;  // per-layer GEMM y output aliases dead K/V^T
  (void)ws_size; (void)in_sizes; (void)n_in; (void)out_size;

  auto cvt = [&](const float* src, u16* dst, long n) {
    int n4 = (int)(n / 4);
    cvt_kernel<<<dim3((n4 + 255) / 256), dim3(256), 0, stream>>>(src, dst, n4);
  };
  cvt(x, xb, 8388608);
  cvt(Wq, wqb, 524288);
  cvt(Wk, wkb, 524288);
  cvt(Wv, wvb, 524288);
  cvt(Wo, wob, 524288);
  cvt(W1, w1b, 2097152);
  cvt(W2, w2b, 2097152);
  cvt(Ew, ewb, 1048576);

  for (int l = 0; l < L_; ++l) {
    const u16* wq = wqb + (long)l * 262144;
    const u16* wk = wkb + (long)l * 262144;
    const u16* wv = wvb + (long)l * 262144;
    const u16* wo = wob + (long)l * 262144;
    const u16* w1 = w1b + (long)l * 1048576;
    const u16* w2 = w2b + (long)l * 1048576;

    // Q = x @ Wq^T -> [B,N,H*D]
    gemm_nt<128, 128, 3><<<dim3(128, 4, 1), dim3(256), 0, stream>>>(
        xb, wq, Qb, nullptr, 512, 512, 512, 512, 0, 0, 0, 1.f);
    // K = x @ Wk^T -> transposed store [B,H*D,N]
    gemm_nt<128, 128, 5><<<dim3(128, 4, 1), dim3(256), 0, stream>>>(
        xb, wk, KVt, nullptr, 512, 512, 512, 0, 0, 0, 0, 1.f);
    // Kp[b,h,k,d] = Ew[k,:] . Kt[b,h*64+d,:] + Eb[k]  (z = b*8+h)
    gemm_nt<64, 64, 4><<<dim3(4, 1, 32), dim3(256), 0, stream>>>(
        ewb, KVt, Kpb, Eb, 4096, 4096, 4096, 64, 0, 262144, 16384, 1.f);
    // V = x @ Wv^T -> transposed store (reuses KVt)
    gemm_nt<128, 128, 5><<<dim3(128, 4, 1), dim3(256), 0, stream>>>(
        xb, wv, KVt, nullptr, 512, 512, 512, 0, 0, 0, 0, 1.f);
    // Vp[b,h,d,k] = Vt[b,h*64+d,:] . Ew[k,:] + Eb[k]
    gemm_nt<64, 64, 3><<<dim3(1, 4, 32), dim3(256), 0, stream>>>(
        KVt, ewb, Vpb, Eb, 4096, 4096, 4096, 256, 262144, 0, 16384, 1.f);

    for (int b = 0; b < B_; ++b) {
      const u16* Qbb = Qb + (long)b * 2097152;
      const u16* Kpp = Kpb + (long)b * 131072;
      const u16* Vpp = Vpb + (long)b * 131072;
      // S[h,n,k] = (Q . Kp) * 0.125 -> bf16 P   (z = h)
      gemm_nt<128, 128, 1><<<dim3(32, 2, 8), dim3(256), 0, stream>>>(
          Qbb, Kpp, Pb, nullptr, 64, 512, 64, 256, 64, 16384, 1048576, 0.125f);
      // softmax over k=256 (8*4096 rows)
      softmax_kernel<<<dim3(8192), dim3(256), 0, stream>>>(Pb);
      // o[n,h*64+d] = P . Vp  -> Ob (aliases Qb rows of this b; QK(b) already done)
      gemm_nt<128, 64, 1><<<dim3(32, 1, 8), dim3(256), 0, stream>>>(
          Pb, Vpp, Ob + (long)b * 2097152, nullptr, 256, 256, 256, 512,
          1048576, 16384, 64, 1.f);
    }

    // y = o @ Wo^T + bo -> bf16 yb
    gemm_nt<128, 128, 3><<<dim3(128, 4, 1), dim3(256), 0, stream>>>(
        Ob, wo, yb, bo + (long)l * 512, 512, 512, 512, 512, 0, 0, 0, 1.f);
    // x = LN(x + y): layer0 reads input x, else d_out (in place)
    add_ln_kernel<<<dim3(4096), dim3(256), 0, stream>>>(
        l == 0 ? x : xc, yb, ln1g + (long)l * 512, ln1b + (long)l * 512, xc, xb);

    // FFN in 4 row-chunks of 4096 (h1 chunk reuses Pb)
    for (int ch = 0; ch < 4; ++ch) {
      const u16* xch = xb + (long)ch * 2097152;
      // h1 = gelu(x @ W1^T + b1) -> bf16 Pb [4096,2048]
      gemm_nt<128, 128, 2><<<dim3(32, 16, 1), dim3(256), 0, stream>>>(
          xch, w1, Pb, b1 + (long)l * 2048, 512, 512, 512, 2048, 0, 0, 0, 1.f);
      // y = h1 @ W2^T + b2 -> bf16 yb chunk
      gemm_nt<128, 128, 3><<<dim3(32, 4, 1), dim3(256), 0, stream>>>(
          Pb, w2, yb + (long)ch * 2097152, b2 + (long)l * 512,
          2048, 2048, 2048, 512, 0, 0, 0, 1.f);
    }
    // x = LN(x + y); final layer leaves result in d_out (xbout null)
    add_ln_kernel<<<dim3(4096), dim3(256), 0, stream>>>(
        xc, yb, ln2g + (long)l * 512, ln2b + (long)l * 512,
        xc, (l == L_ - 1) ? (u16*)nullptr : xb);
  }
}

// Round 3
// 1158.128 us; speedup vs baseline: 1.3312x; 1.3312x over previous
//
#include <hip/hip_runtime.h>
#include <math.h>

typedef unsigned short u16;
typedef __attribute__((ext_vector_type(8))) short short8;
typedef __attribute__((ext_vector_type(4))) float f32x4;

#define B_ 4
#define N_ 4096
#define C_ 512
#define H_ 8
#define D_ 64
#define KD_ 256
#define FF_ 2048
#define L_ 2

__device__ __forceinline__ float bf2f(u16 x) {
  return __builtin_bit_cast(float, (unsigned int)x << 16);
}
__device__ __forceinline__ u16 f2bf(float f) {
  unsigned int t = __builtin_bit_cast(unsigned int, f);
  return (u16)((t + 0x7fffu + ((t >> 16) & 1u)) >> 16);
}

// async global->LDS, 16B per lane
#define GLD(g, l)                                                             \
  __builtin_amdgcn_global_load_lds(                                           \
      (const __attribute__((address_space(1))) void*)(g),                     \
      (__attribute__((address_space(3))) void*)(l), 16, 0, 0)

// ---------------- f32 -> bf16 convert ----------------
__global__ __launch_bounds__(256) void cvt_kernel(const float* __restrict__ in,
                                                  u16* __restrict__ out, int n4) {
  int i = blockIdx.x * 256 + threadIdx.x;
  if (i >= n4) return;
  float4 v = reinterpret_cast<const float4*>(in)[i];
  ushort4 o;
  o.x = f2bf(v.x); o.y = f2bf(v.y); o.z = f2bf(v.z); o.w = f2bf(v.w);
  reinterpret_cast<ushort4*>(out)[i] = o;
}

// ---------------- bf16 transpose [B,N,C] -> [B,C,N], 64x64 tiles ----------------
__global__ __launch_bounds__(256) void transpose_kernel(const u16* __restrict__ in,
                                                        u16* __restrict__ out) {
  __shared__ u16 T[64][72];
  int n0 = blockIdx.x * 64, c0 = blockIdx.y * 64, b = blockIdx.z;
  const u16* src = in + (long)b * N_ * C_;
  u16* dst = out + (long)b * C_ * N_;
  int t = threadIdx.x;
  int r = t >> 3, cq = (t & 7) * 8;
#pragma unroll
  for (int h = 0; h < 2; ++h) {
    const u16* p = src + (long)(n0 + r + h * 32) * C_ + c0 + cq;
    ushort4 v0 = *reinterpret_cast<const ushort4*>(p);
    ushort4 v1 = *reinterpret_cast<const ushort4*>(p + 4);
    T[r + h * 32][cq + 0] = v0.x; T[r + h * 32][cq + 1] = v0.y;
    T[r + h * 32][cq + 2] = v0.z; T[r + h * 32][cq + 3] = v0.w;
    T[r + h * 32][cq + 4] = v1.x; T[r + h * 32][cq + 5] = v1.y;
    T[r + h * 32][cq + 6] = v1.z; T[r + h * 32][cq + 7] = v1.w;
  }
  __syncthreads();
  int cc = t >> 3, nq = (t & 7) * 8;
#pragma unroll
  for (int h = 0; h < 2; ++h) {
    int cl = cc + h * 32;
    ushort4 w0, w1;
    w0.x = T[nq + 0][cl]; w0.y = T[nq + 1][cl];
    w0.z = T[nq + 2][cl]; w0.w = T[nq + 3][cl];
    w1.x = T[nq + 4][cl]; w1.y = T[nq + 5][cl];
    w1.z = T[nq + 6][cl]; w1.w = T[nq + 7][cl];
    u16* q = dst + (long)(c0 + cl) * N_ + n0 + nq;
    *reinterpret_cast<ushort4*>(q) = w0;
    *reinterpret_cast<ushort4*>(q + 4) = w1;
  }
}

// ---------------- generic NT MFMA GEMM (global_load_lds staging) ----------------
// C[m,j] = sum_k A[m,k]*B[j,k]; z-batch strides sA1/sB1/sC1; split-K via sCh.
// EPI: 1 bf16 *alpha | 2 bf16 gelu(v+bias[j]) | 3 bf16 +bias[j](nullable)
//      4 bf16 +bias[m] | 6 bf16 transposed store [j,m] +bias[m] | 7 f32 partial
template <int BM, int BN, int EPI, int SPLITK>
__global__ __launch_bounds__(256, 2) void gemm_nt(
    const u16* __restrict__ A, const u16* __restrict__ B, void* __restrict__ Cout,
    const float* __restrict__ bias, int K, int lda, int ldb, int ldc,
    long sA1, long sB1, long sC1, long sCh, int nz, float alpha) {
  constexpr int BK = 64;
  constexpr int WM = BM / 2, WN = BN / 2;
  constexpr int FM = WM / 16, FN = WN / 16;
  constexpr int CA = BM / 32, CB = BN / 32;  // 16B lds-loads per thread

  __shared__ __attribute__((aligned(16))) u16 As[BM * BK];
  __shared__ __attribute__((aligned(16))) u16 Bs[BN * BK];

  int z, chunk;
  if constexpr (SPLITK > 1) { z = blockIdx.z % nz; chunk = blockIdx.z / nz; }
  else { z = blockIdx.z; chunk = 0; }
  A += (long)z * sA1;
  B += (long)z * sB1;
  long coff = (long)z * sC1 + (long)chunk * sCh;

  int tid = threadIdx.x;
  int lane = tid & 63, wid = tid >> 6;
  int wr = wid >> 1, wc = wid & 1;
  int row0 = blockIdx.x * BM, col0 = blockIdx.y * BN;

  int Kc = K / SPLITK;
  int kbeg = chunk * Kc;

  f32x4 acc[FM][FN] = {};

  for (int k0 = kbeg; k0 < kbeg + Kc; k0 += BK) {
#pragma unroll
    for (int i = 0; i < CA; ++i) {
      int c = tid + i * 256;
      GLD(A + (long)(row0 + (c >> 3)) * lda + k0 + (c & 7) * 8, As + c * 8);
    }
#pragma unroll
    for (int i = 0; i < CB; ++i) {
      int c = tid + i * 256;
      GLD(B + (long)(col0 + (c >> 3)) * ldb + k0 + (c & 7) * 8, Bs + c * 8);
    }
    __syncthreads();

    int lr = lane & 15, lk = (lane >> 4) * 8;
#pragma unroll
    for (int kk = 0; kk < BK; kk += 32) {
      short8 af[FM], bfr[FN];
#pragma unroll
      for (int mi = 0; mi < FM; ++mi)
        af[mi] = *reinterpret_cast<const short8*>(&As[(wr * WM + mi * 16 + lr) * BK + kk + lk]);
#pragma unroll
      for (int nj = 0; nj < FN; ++nj)
        bfr[nj] = *reinterpret_cast<const short8*>(&Bs[(wc * WN + nj * 16 + lr) * BK + kk + lk]);
#pragma unroll
      for (int mi = 0; mi < FM; ++mi)
#pragma unroll
        for (int nj = 0; nj < FN; ++nj)
          acc[mi][nj] = __builtin_amdgcn_mfma_f32_16x16x32_bf16(af[mi], bfr[nj], acc[mi][nj], 0, 0, 0);
    }
    __syncthreads();
  }

  // epilogue: C/D layout col=lane&15, row=(lane>>4)*4+reg
  int lc = lane & 15, rb = (lane >> 4) * 4;
#pragma unroll
  for (int mi = 0; mi < FM; ++mi) {
#pragma unroll
    for (int nj = 0; nj < FN; ++nj) {
      int j = col0 + wc * WN + nj * 16 + lc;
      int m0 = row0 + wr * WM + mi * 16 + rb;
#pragma unroll
      for (int r = 0; r < 4; ++r) {
        int m = m0 + r;
        float v = acc[mi][nj][r];
        if constexpr (EPI == 1) {
          reinterpret_cast<u16*>(Cout)[coff + (long)m * ldc + j] = f2bf(v * alpha);
        } else if constexpr (EPI == 2) {
          float t = v + bias[j];
          float gl = 0.5f * t * (1.f + erff(t * 0.70710678118f));
          reinterpret_cast<u16*>(Cout)[coff + (long)m * ldc + j] = f2bf(gl);
        } else if constexpr (EPI == 3) {
          float bi = bias ? bias[j] : 0.f;
          reinterpret_cast<u16*>(Cout)[coff + (long)m * ldc + j] = f2bf(v + bi);
        } else if constexpr (EPI == 4) {
          reinterpret_cast<u16*>(Cout)[coff + (long)m * ldc + j] = f2bf(v + bias[m]);
        } else if constexpr (EPI == 6) {
          reinterpret_cast<u16*>(Cout)[coff + (long)j * ldc + m] = f2bf(v + bias[m]);
        } else {  // 7: f32 split-K partial
          reinterpret_cast<float*>(Cout)[coff + (long)m * ldc + j] = v;
        }
      }
    }
  }
}

// ---------------- split-K reduce: sum 8 f32 chunks -> bf16 ----------------
__global__ __launch_bounds__(256) void reduce8_kernel(const float* __restrict__ part,
                                                      u16* __restrict__ out) {
  int i = blockIdx.x * 256 + threadIdx.x;  // float4 index, 131072 total
  const float4* p = reinterpret_cast<const float4*>(part);
  float4 s = p[i];
#pragma unroll
  for (int c = 1; c < 8; ++c) {
    float4 t = p[i + c * 131072];
    s.x += t.x; s.y += t.y; s.z += t.z; s.w += t.w;
  }
  ushort4 o;
  o.x = f2bf(s.x); o.y = f2bf(s.y); o.z = f2bf(s.z); o.w = f2bf(s.w);
  reinterpret_cast<ushort4*>(out)[i] = o;
}

// ---------------- softmax over rows of 256 (bf16 in/out, in place) ----------------
__global__ __launch_bounds__(256) void softmax_kernel(u16* __restrict__ P) {
  long row = (long)blockIdx.x * 4 + (threadIdx.x >> 6);
  int lane = threadIdx.x & 63;
  u16* p = P + row * KD_ + lane * 4;
  ushort4 u = *reinterpret_cast<const ushort4*>(p);
  float v0 = bf2f(u.x), v1 = bf2f(u.y), v2 = bf2f(u.z), v3 = bf2f(u.w);
  float mx = fmaxf(fmaxf(v0, v1), fmaxf(v2, v3));
#pragma unroll
  for (int o = 1; o < 64; o <<= 1) mx = fmaxf(mx, __shfl_xor(mx, o));
  float e0 = __expf(v0 - mx), e1 = __expf(v1 - mx), e2 = __expf(v2 - mx), e3 = __expf(v3 - mx);
  float sm = e0 + e1 + e2 + e3;
#pragma unroll
  for (int o = 1; o < 64; o <<= 1) sm += __shfl_xor(sm, o);
  float inv = 1.f / sm;
  ushort4 w;
  w.x = f2bf(e0 * inv); w.y = f2bf(e1 * inv); w.z = f2bf(e2 * inv); w.w = f2bf(e3 * inv);
  *reinterpret_cast<ushort4*>(p) = w;
}

// ---------------- residual add + LayerNorm (row of 512) ----------------
__global__ __launch_bounds__(256) void add_ln_kernel(
    const float* __restrict__ xin, const u16* __restrict__ yin,
    const float* __restrict__ g, const float* __restrict__ bt,
    float* __restrict__ xout, u16* __restrict__ xbout) {
  int row = blockIdx.x * 4 + (threadIdx.x >> 6);
  int lane = threadIdx.x & 63;
  long base = (long)row * C_ + lane * 8;
  float4 a0 = *reinterpret_cast<const float4*>(xin + base);
  float4 a1 = *reinterpret_cast<const float4*>(xin + base + 4);
  ushort4 u0 = *reinterpret_cast<const ushort4*>(yin + base);
  ushort4 u1 = *reinterpret_cast<const ushort4*>(yin + base + 4);
  float s[8] = {a0.x + bf2f(u0.x), a0.y + bf2f(u0.y), a0.z + bf2f(u0.z), a0.w + bf2f(u0.w),
                a1.x + bf2f(u1.x), a1.y + bf2f(u1.y), a1.z + bf2f(u1.z), a1.w + bf2f(u1.w)};
  float sum = 0.f;
#pragma unroll
  for (int i = 0; i < 8; ++i) sum += s[i];
#pragma unroll
  for (int o = 1; o < 64; o <<= 1) sum += __shfl_xor(sum, o);
  float mean = sum * (1.f / C_);
  float var = 0.f;
#pragma unroll
  for (int i = 0; i < 8; ++i) { float d = s[i] - mean; var += d * d; }
#pragma unroll
  for (int o = 1; o < 64; o <<= 1) var += __shfl_xor(var, o);
  float inv = rsqrtf(var * (1.f / C_) + 1e-5f);
  int c0 = lane * 8;
#pragma unroll
  for (int i = 0; i < 8; ++i) {
    float o = (s[i] - mean) * inv * g[c0 + i] + bt[c0 + i];
    xout[base + i] = o;
    if (xbout) xbout[base + i] = f2bf(o);
  }
}

extern "C" void kernel_launch(void* const* d_in, const int* in_sizes, int n_in,
                              void* d_out, int out_size, void* d_ws, size_t ws_size,
                              hipStream_t stream) {
  const float* x    = (const float*)d_in[0];
  const float* Wq   = (const float*)d_in[1];
  const float* Wk   = (const float*)d_in[2];
  const float* Wv   = (const float*)d_in[3];
  const float* Wo   = (const float*)d_in[4];
  const float* bo   = (const float*)d_in[5];
  const float* ln1g = (const float*)d_in[6];
  const float* ln1b = (const float*)d_in[7];
  const float* W1   = (const float*)d_in[8];
  const float* b1   = (const float*)d_in[9];
  const float* W2   = (const float*)d_in[10];
  const float* b2   = (const float*)d_in[11];
  const float* ln2g = (const float*)d_in[12];
  const float* ln2b = (const float*)d_in[13];
  const float* Ew   = (const float*)d_in[14];
  const float* Eb   = (const float*)d_in[15];
  float* xc = (float*)d_out;  // running residual x (f32), in-place LN; final = output

  // workspace ~81 MB, write-before-read every call
  char* wsp = (char*)d_ws;
  size_t off = 0;
  auto alloc = [&](size_t bytes) -> void* {
    void* p = wsp + off;
    off = (off + bytes + 255) & ~(size_t)255;
    return p;
  };
  u16* xb  = (u16*)alloc(8388608UL * 2);  // x bf16 [B,N,C]
  u16* xT  = (u16*)alloc(8388608UL * 2);  // x^T [B,C,N]; later y (bf16 [B,N,C])
  u16* Qb  = (u16*)alloc(8388608UL * 2);  // Q [B,N,H*D]; attn-out aliases per-b
  u16* Pb  = (u16*)alloc(8388608UL * 2);  // xE f32 partials / P per-b [H,N,KD] / h1 chunk
  u16* xEb = (u16*)alloc(524288UL * 2);   // xE bf16 [B,KD,C]
  u16* Kpb = (u16*)alloc(524288UL * 2);   // Kp [B,KD,H*D]
  u16* Vpt = (u16*)alloc(524288UL * 2);   // Vp^T [B,H*D,KD]
  u16* wqb = (u16*)alloc(524288UL * 2);
  u16* wkb = (u16*)alloc(524288UL * 2);
  u16* wvb = (u16*)alloc(524288UL * 2);
  u16* wob = (u16*)alloc(524288UL * 2);
  u16* w1b = (u16*)alloc(2097152UL * 2);
  u16* w2b = (u16*)alloc(2097152UL * 2);
  u16* ewb = (u16*)alloc(1048576UL * 2);
  u16* Ob = Qb;              // attn output aliases Q
  u16* yb = xT;              // per-layer GEMM y output aliases dead x^T
  float* partF = (float*)Pb; // split-K partials alias P
  (void)ws_size; (void)in_sizes; (void)n_in; (void)out_size;

  auto cvt = [&](const float* src, u16* dst, long n) {
    int n4 = (int)(n / 4);
    cvt_kernel<<<dim3((n4 + 255) / 256), dim3(256), 0, stream>>>(src, dst, n4);
  };
  cvt(x, xb, 8388608);
  cvt(Wq, wqb, 524288);
  cvt(Wk, wkb, 524288);
  cvt(Wv, wvb, 524288);
  cvt(Wo, wob, 524288);
  cvt(W1, w1b, 2097152);
  cvt(W2, w2b, 2097152);
  cvt(Ew, ewb, 1048576);

  for (int l = 0; l < L_; ++l) {
    const u16* wq = wqb + (long)l * 262144;
    const u16* wk = wkb + (long)l * 262144;
    const u16* wv = wvb + (long)l * 262144;
    const u16* wo = wob + (long)l * 262144;
    const u16* w1 = w1b + (long)l * 1048576;
    const u16* w2 = w2b + (long)l * 1048576;

    // x^T [B,C,N]
    transpose_kernel<<<dim3(64, 8, 4), dim3(256), 0, stream>>>(xb, xT);
    // xE partials: xE[b,k,c] = Ew[k,:] . xT[b,c,:]  (split-K=8 over n)
    gemm_nt<128, 128, 7, 8><<<dim3(2, 4, 32), dim3(256), 0, stream>>>(
        ewb, xT, partF, nullptr, 4096, 4096, 4096, 512,
        0, 2097152, 131072, 524288, 4, 1.f);
    reduce8_kernel<<<dim3(512), dim3(256), 0, stream>>>(partF, xEb);
    // Kp[b,k,hd] = xE . Wk^T + Eb[k]
    gemm_nt<128, 128, 4, 1><<<dim3(2, 4, 4), dim3(256), 0, stream>>>(
        xEb, wk, Kpb, Eb, 512, 512, 512, 512, 131072, 0, 131072, 0, 4, 1.f);
    // Vp^T[b,hd,k] = (xE . Wv^T)^T + Eb[k]
    gemm_nt<128, 128, 6, 1><<<dim3(2, 4, 4), dim3(256), 0, stream>>>(
        xEb, wv, Vpt, Eb, 512, 512, 512, 256, 131072, 0, 131072, 0, 4, 1.f);
    // Q = x @ Wq^T -> [B,N,H*D]
    gemm_nt<128, 128, 3, 1><<<dim3(128, 4, 1), dim3(256), 0, stream>>>(
        xb, wq, Qb, nullptr, 512, 512, 512, 512, 0, 0, 0, 0, 1, 1.f);

    for (int b = 0; b < B_; ++b) {
      const u16* Qbb = Qb + (long)b * 2097152;
      // S[h,n,k] = (Q_h . Kp_h) * 0.125  (z = h)
      gemm_nt<128, 128, 1, 1><<<dim3(32, 2, 8), dim3(256), 0, stream>>>(
          Qbb, Kpb + (long)b * 131072, Pb, nullptr, 64, 512, 512, 256,
          64, 64, 1048576, 0, 8, 0.125f);
      softmax_kernel<<<dim3(8192), dim3(256), 0, stream>>>(Pb);
      // o[n,h*64+d] = P_h . Vp^T_h
      gemm_nt<128, 64, 1, 1><<<dim3(32, 1, 8), dim3(256), 0, stream>>>(
          Pb, Vpt + (long)b * 131072, Ob + (long)b * 2097152, nullptr,
          256, 256, 256, 512, 1048576, 16384, 64, 0, 8, 1.f);
    }

    // y = o @ Wo^T + bo -> bf16 yb
    gemm_nt<128, 128, 3, 1><<<dim3(128, 4, 1), dim3(256), 0, stream>>>(
        Ob, wo, yb, bo + (long)l * 512, 512, 512, 512, 512, 0, 0, 0, 0, 1, 1.f);
    // x = LN(x + y)
    add_ln_kernel<<<dim3(4096), dim3(256), 0, stream>>>(
        l == 0 ? x : xc, yb, ln1g + (long)l * 512, ln1b + (long)l * 512, xc, xb);

    // FFN in 4 row-chunks of 4096 (h1 chunk reuses Pb)
    for (int ch = 0; ch < 4; ++ch) {
      const u16* xch = xb + (long)ch * 2097152;
      gemm_nt<128, 128, 2, 1><<<dim3(32, 16, 1), dim3(256), 0, stream>>>(
          xch, w1, Pb, b1 + (long)l * 2048, 512, 512, 512, 2048, 0, 0, 0, 0, 1, 1.f);
      gemm_nt<128, 128, 3, 1><<<dim3(32, 4, 1), dim3(256), 0, stream>>>(
          Pb, w2, yb + (long)ch * 2097152, b2 + (long)l * 512,
          2048, 2048, 2048, 512, 0, 0, 0, 0, 1, 1.f);
    }
    // x = LN(x + y); final layer leaves f32 result in d_out
    add_ln_kernel<<<dim3(4096), dim3(256), 0, stream>>>(
        xc, yb, ln2g + (long)l * 512, ln2b + (long)l * 512,
        xc, (l == L_ - 1) ? (u16*)nullptr : xb);
  }
}

// Round 4
// 719.588 us; speedup vs baseline: 2.1425x; 1.6094x over previous
//
#include <hip/hip_runtime.h>
#include <math.h>

typedef unsigned short u16;
typedef __attribute__((ext_vector_type(8))) short short8;
typedef __attribute__((ext_vector_type(4))) float f32x4;

#define B_ 4
#define N_ 4096
#define C_ 512
#define H_ 8
#define D_ 64
#define KD_ 256
#define FF_ 2048
#define L_ 2

__device__ __forceinline__ float bf2f(u16 x) {
  return __builtin_bit_cast(float, (unsigned int)x << 16);
}
__device__ __forceinline__ u16 f2bf(float f) {
  unsigned int t = __builtin_bit_cast(unsigned int, f);
  return (u16)((t + 0x7fffu + ((t >> 16) & 1u)) >> 16);
}

// async global->LDS, 16B per lane
#define GLD(g, l)                                                             \
  __builtin_amdgcn_global_load_lds(                                           \
      (const __attribute__((address_space(1))) void*)(g),                     \
      (__attribute__((address_space(3))) void*)(l), 16, 0, 0)

// ---------------- f32 -> bf16 convert ----------------
__global__ __launch_bounds__(256) void cvt_kernel(const float* __restrict__ in,
                                                  u16* __restrict__ out, int n4) {
  int i = blockIdx.x * 256 + threadIdx.x;
  if (i >= n4) return;
  float4 v = reinterpret_cast<const float4*>(in)[i];
  ushort4 o;
  o.x = f2bf(v.x); o.y = f2bf(v.y); o.z = f2bf(v.z); o.w = f2bf(v.w);
  reinterpret_cast<ushort4*>(out)[i] = o;
}

// ---------------- bf16 transpose [B,N,C] -> [B,C,N], 64x64 tiles ----------------
__global__ __launch_bounds__(256) void transpose_kernel(const u16* __restrict__ in,
                                                        u16* __restrict__ out) {
  __shared__ u16 T[64][72];
  int n0 = blockIdx.x * 64, c0 = blockIdx.y * 64, b = blockIdx.z;
  const u16* src = in + (long)b * N_ * C_;
  u16* dst = out + (long)b * C_ * N_;
  int t = threadIdx.x;
  int r = t >> 3, cq = (t & 7) * 8;
#pragma unroll
  for (int h = 0; h < 2; ++h) {
    const u16* p = src + (long)(n0 + r + h * 32) * C_ + c0 + cq;
    ushort4 v0 = *reinterpret_cast<const ushort4*>(p);
    ushort4 v1 = *reinterpret_cast<const ushort4*>(p + 4);
    T[r + h * 32][cq + 0] = v0.x; T[r + h * 32][cq + 1] = v0.y;
    T[r + h * 32][cq + 2] = v0.z; T[r + h * 32][cq + 3] = v0.w;
    T[r + h * 32][cq + 4] = v1.x; T[r + h * 32][cq + 5] = v1.y;
    T[r + h * 32][cq + 6] = v1.z; T[r + h * 32][cq + 7] = v1.w;
  }
  __syncthreads();
  int cc = t >> 3, nq = (t & 7) * 8;
#pragma unroll
  for (int h = 0; h < 2; ++h) {
    int cl = cc + h * 32;
    ushort4 w0, w1;
    w0.x = T[nq + 0][cl]; w0.y = T[nq + 1][cl];
    w0.z = T[nq + 2][cl]; w0.w = T[nq + 3][cl];
    w1.x = T[nq + 4][cl]; w1.y = T[nq + 5][cl];
    w1.z = T[nq + 6][cl]; w1.w = T[nq + 7][cl];
    u16* q = dst + (long)(c0 + cl) * N_ + n0 + nq;
    *reinterpret_cast<ushort4*>(q) = w0;
    *reinterpret_cast<ushort4*>(q + 4) = w1;
  }
}

// ---------------- generic NT MFMA GEMM (global_load_lds staging) ----------------
// C[m,j] = sum_k A[m,k]*B[j,k]; two-level z batch (zb=z>>3, zh=z&7); split-K sCh.
// EPI: 1 bf16 *alpha | 2 bf16 gelu(v+bias[j]) | 3 bf16 +bias[j](nullable)
//      4 bf16 +bias[m] | 6 bf16 transposed store [j,m] +bias[m] | 7 f32 partial
template <int BM, int BN, int EPI, int SPLITK>
__global__ __launch_bounds__(256, 2) void gemm_nt(
    const u16* __restrict__ A, const u16* __restrict__ B, void* __restrict__ Cout,
    const float* __restrict__ bias, int K, int lda, int ldb, int ldc,
    long sA0, long sA1, long sB0, long sB1, long sC0, long sC1, long sCh,
    int nz, float alpha) {
  constexpr int BK = 64;
  constexpr int WM = BM / 2, WN = BN / 2;
  constexpr int FM = WM / 16, FN = WN / 16;
  constexpr int CA = BM / 32, CB = BN / 32;  // 16B lds-loads per thread

  __shared__ __attribute__((aligned(16))) u16 As[BM * BK];
  __shared__ __attribute__((aligned(16))) u16 Bs[BN * BK];

  int z, chunk;
  if constexpr (SPLITK > 1) { z = blockIdx.z % nz; chunk = blockIdx.z / nz; }
  else { z = blockIdx.z; chunk = 0; }
  int zb = z >> 3, zh = z & 7;
  A += (long)zb * sA0 + (long)zh * sA1;
  B += (long)zb * sB0 + (long)zh * sB1;
  long coff = (long)zb * sC0 + (long)zh * sC1 + (long)chunk * sCh;

  int tid = threadIdx.x;
  int lane = tid & 63, wid = tid >> 6;
  int wr = wid >> 1, wc = wid & 1;
  int row0 = blockIdx.x * BM, col0 = blockIdx.y * BN;

  int Kc = K / SPLITK;
  int kbeg = chunk * Kc;

  f32x4 acc[FM][FN] = {};

  for (int k0 = kbeg; k0 < kbeg + Kc; k0 += BK) {
#pragma unroll
    for (int i = 0; i < CA; ++i) {
      int c = tid + i * 256;
      GLD(A + (long)(row0 + (c >> 3)) * lda + k0 + (c & 7) * 8, As + c * 8);
    }
#pragma unroll
    for (int i = 0; i < CB; ++i) {
      int c = tid + i * 256;
      GLD(B + (long)(col0 + (c >> 3)) * ldb + k0 + (c & 7) * 8, Bs + c * 8);
    }
    __syncthreads();

    int lr = lane & 15, lk = (lane >> 4) * 8;
#pragma unroll
    for (int kk = 0; kk < BK; kk += 32) {
      short8 af[FM], bfr[FN];
#pragma unroll
      for (int mi = 0; mi < FM; ++mi)
        af[mi] = *reinterpret_cast<const short8*>(&As[(wr * WM + mi * 16 + lr) * BK + kk + lk]);
#pragma unroll
      for (int nj = 0; nj < FN; ++nj)
        bfr[nj] = *reinterpret_cast<const short8*>(&Bs[(wc * WN + nj * 16 + lr) * BK + kk + lk]);
#pragma unroll
      for (int mi = 0; mi < FM; ++mi)
#pragma unroll
        for (int nj = 0; nj < FN; ++nj)
          acc[mi][nj] = __builtin_amdgcn_mfma_f32_16x16x32_bf16(af[mi], bfr[nj], acc[mi][nj], 0, 0, 0);
    }
    __syncthreads();
  }

  // epilogue: C/D layout col=lane&15, row=(lane>>4)*4+reg
  int lc = lane & 15, rb = (lane >> 4) * 4;
#pragma unroll
  for (int mi = 0; mi < FM; ++mi) {
#pragma unroll
    for (int nj = 0; nj < FN; ++nj) {
      int j = col0 + wc * WN + nj * 16 + lc;
      int m0 = row0 + wr * WM + mi * 16 + rb;
#pragma unroll
      for (int r = 0; r < 4; ++r) {
        int m = m0 + r;
        float v = acc[mi][nj][r];
        if constexpr (EPI == 1) {
          reinterpret_cast<u16*>(Cout)[coff + (long)m * ldc + j] = f2bf(v * alpha);
        } else if constexpr (EPI == 2) {
          float t = v + bias[j];
          float gl = 0.5f * t * (1.f + erff(t * 0.70710678118f));
          reinterpret_cast<u16*>(Cout)[coff + (long)m * ldc + j] = f2bf(gl);
        } else if constexpr (EPI == 3) {
          float bi = bias ? bias[j] : 0.f;
          reinterpret_cast<u16*>(Cout)[coff + (long)m * ldc + j] = f2bf(v + bi);
        } else if constexpr (EPI == 4) {
          reinterpret_cast<u16*>(Cout)[coff + (long)m * ldc + j] = f2bf(v + bias[m]);
        } else if constexpr (EPI == 6) {
          reinterpret_cast<u16*>(Cout)[coff + (long)j * ldc + m] = f2bf(v + bias[m]);
        } else {  // 7: f32 split-K partial
          reinterpret_cast<float*>(Cout)[coff + (long)m * ldc + j] = v;
        }
      }
    }
  }
}

// ---------------- split-K reduce: sum 8 f32 chunks -> bf16 ----------------
__global__ __launch_bounds__(256) void reduce8_kernel(const float* __restrict__ part,
                                                      u16* __restrict__ out) {
  int i = blockIdx.x * 256 + threadIdx.x;  // float4 index, 131072 total
  const float4* p = reinterpret_cast<const float4*>(part);
  float4 s = p[i];
#pragma unroll
  for (int c = 1; c < 8; ++c) {
    float4 t = p[i + c * 131072];
    s.x += t.x; s.y += t.y; s.z += t.z; s.w += t.w;
  }
  ushort4 o;
  o.x = f2bf(s.x); o.y = f2bf(s.y); o.z = f2bf(s.z); o.w = f2bf(s.w);
  reinterpret_cast<ushort4*>(out)[i] = o;
}

// ---------------- softmax over rows of 256 (bf16 in/out, in place) ----------------
__global__ __launch_bounds__(256) void softmax_kernel(u16* __restrict__ P) {
  long row = (long)blockIdx.x * 4 + (threadIdx.x >> 6);
  int lane = threadIdx.x & 63;
  u16* p = P + row * KD_ + lane * 4;
  ushort4 u = *reinterpret_cast<const ushort4*>(p);
  float v0 = bf2f(u.x), v1 = bf2f(u.y), v2 = bf2f(u.z), v3 = bf2f(u.w);
  float mx = fmaxf(fmaxf(v0, v1), fmaxf(v2, v3));
#pragma unroll
  for (int o = 1; o < 64; o <<= 1) mx = fmaxf(mx, __shfl_xor(mx, o));
  float e0 = __expf(v0 - mx), e1 = __expf(v1 - mx), e2 = __expf(v2 - mx), e3 = __expf(v3 - mx);
  float sm = e0 + e1 + e2 + e3;
#pragma unroll
  for (int o = 1; o < 64; o <<= 1) sm += __shfl_xor(sm, o);
  float inv = 1.f / sm;
  ushort4 w;
  w.x = f2bf(e0 * inv); w.y = f2bf(e1 * inv); w.z = f2bf(e2 * inv); w.w = f2bf(e3 * inv);
  *reinterpret_cast<ushort4*>(p) = w;
}

// ---------------- residual add + LayerNorm (row of 512), bf16 residual stream --------
// xin32 (layer0) XOR xinb; yin bf16; outputs: xout32 (final) and/or xbout (bf16)
__global__ __launch_bounds__(256) void add_ln_kernel(
    const float* __restrict__ xin32, const u16* __restrict__ xinb,
    const u16* __restrict__ yin, const float* __restrict__ g,
    const float* __restrict__ bt, float* __restrict__ xout32,
    u16* __restrict__ xbout) {
  int row = blockIdx.x * 4 + (threadIdx.x >> 6);
  int lane = threadIdx.x & 63;
  long base = (long)row * C_ + lane * 8;
  float s[8];
  if (xin32) {
    float4 a0 = *reinterpret_cast<const float4*>(xin32 + base);
    float4 a1 = *reinterpret_cast<const float4*>(xin32 + base + 4);
    s[0] = a0.x; s[1] = a0.y; s[2] = a0.z; s[3] = a0.w;
    s[4] = a1.x; s[5] = a1.y; s[6] = a1.z; s[7] = a1.w;
  } else {
    ushort4 x0 = *reinterpret_cast<const ushort4*>(xinb + base);
    ushort4 x1 = *reinterpret_cast<const ushort4*>(xinb + base + 4);
    s[0] = bf2f(x0.x); s[1] = bf2f(x0.y); s[2] = bf2f(x0.z); s[3] = bf2f(x0.w);
    s[4] = bf2f(x1.x); s[5] = bf2f(x1.y); s[6] = bf2f(x1.z); s[7] = bf2f(x1.w);
  }
  ushort4 u0 = *reinterpret_cast<const ushort4*>(yin + base);
  ushort4 u1 = *reinterpret_cast<const ushort4*>(yin + base + 4);
  s[0] += bf2f(u0.x); s[1] += bf2f(u0.y); s[2] += bf2f(u0.z); s[3] += bf2f(u0.w);
  s[4] += bf2f(u1.x); s[5] += bf2f(u1.y); s[6] += bf2f(u1.z); s[7] += bf2f(u1.w);
  float sum = 0.f;
#pragma unroll
  for (int i = 0; i < 8; ++i) sum += s[i];
#pragma unroll
  for (int o = 1; o < 64; o <<= 1) sum += __shfl_xor(sum, o);
  float mean = sum * (1.f / C_);
  float var = 0.f;
#pragma unroll
  for (int i = 0; i < 8; ++i) { float d = s[i] - mean; var += d * d; }
#pragma unroll
  for (int o = 1; o < 64; o <<= 1) var += __shfl_xor(var, o);
  float inv = rsqrtf(var * (1.f / C_) + 1e-5f);
  int c0 = lane * 8;
  float o[8];
#pragma unroll
  for (int i = 0; i < 8; ++i) o[i] = (s[i] - mean) * inv * g[c0 + i] + bt[c0 + i];
  if (xout32) {
    float4 f0 = {o[0], o[1], o[2], o[3]};
    float4 f1 = {o[4], o[5], o[6], o[7]};
    *reinterpret_cast<float4*>(xout32 + base) = f0;
    *reinterpret_cast<float4*>(xout32 + base + 4) = f1;
  }
  if (xbout) {
    ushort4 w0 = {f2bf(o[0]), f2bf(o[1]), f2bf(o[2]), f2bf(o[3])};
    ushort4 w1 = {f2bf(o[4]), f2bf(o[5]), f2bf(o[6]), f2bf(o[7])};
    *reinterpret_cast<ushort4*>(xbout + base) = w0;
    *reinterpret_cast<ushort4*>(xbout + base + 4) = w1;
  }
}

extern "C" void kernel_launch(void* const* d_in, const int* in_sizes, int n_in,
                              void* d_out, int out_size, void* d_ws, size_t ws_size,
                              hipStream_t stream) {
  const float* x    = (const float*)d_in[0];
  const float* Wq   = (const float*)d_in[1];
  const float* Wk   = (const float*)d_in[2];
  const float* Wv   = (const float*)d_in[3];
  const float* Wo   = (const float*)d_in[4];
  const float* bo   = (const float*)d_in[5];
  const float* ln1g = (const float*)d_in[6];
  const float* ln1b = (const float*)d_in[7];
  const float* W1   = (const float*)d_in[8];
  const float* b1   = (const float*)d_in[9];
  const float* W2   = (const float*)d_in[10];
  const float* b2   = (const float*)d_in[11];
  const float* ln2g = (const float*)d_in[12];
  const float* ln2b = (const float*)d_in[13];
  const float* Ew   = (const float*)d_in[14];
  const float* Eb   = (const float*)d_in[15];
  float* xc = (float*)d_out;  // final f32 output only

  // workspace ~97 MB, write-before-read every call
  char* wsp = (char*)d_ws;
  size_t off = 0;
  auto alloc = [&](size_t bytes) -> void* {
    void* p = wsp + off;
    off = (off + bytes + 255) & ~(size_t)255;
    return p;
  };
  u16* xb  = (u16*)alloc(8388608UL * 2);   // x bf16 [B,N,C]
  u16* BIG = (u16*)alloc(16777216UL * 2);  // 32MB: xT+xE-partials | P half | h1 chunk
  u16* Qb  = (u16*)alloc(8388608UL * 2);   // Q [B,N,H*D]; attn-out aliases per half
  u16* yb  = (u16*)alloc(8388608UL * 2);   // y bf16 [B,N,C]
  u16* xEb = (u16*)alloc(524288UL * 2);    // xE bf16 [B,KD,C]
  u16* Kpb = (u16*)alloc(524288UL * 2);    // Kp [B,KD,H*D]
  u16* Vpt = (u16*)alloc(524288UL * 2);    // Vp^T [B,H*D,KD]
  u16* wqb = (u16*)alloc(524288UL * 2);
  u16* wkb = (u16*)alloc(524288UL * 2);
  u16* wvb = (u16*)alloc(524288UL * 2);
  u16* wob = (u16*)alloc(524288UL * 2);
  u16* w1b = (u16*)alloc(2097152UL * 2);
  u16* w2b = (u16*)alloc(2097152UL * 2);
  u16* ewb = (u16*)alloc(1048576UL * 2);
  u16* Ob = Qb;  // attn output aliases Q (per half, after that half's QK)
  (void)ws_size; (void)in_sizes; (void)n_in; (void)out_size;

  auto cvt = [&](const float* src, u16* dst, long n) {
    int n4 = (int)(n / 4);
    cvt_kernel<<<dim3((n4 + 255) / 256), dim3(256), 0, stream>>>(src, dst, n4);
  };
  cvt(x, xb, 8388608);
  cvt(Wq, wqb, 524288);
  cvt(Wk, wkb, 524288);
  cvt(Wv, wvb, 524288);
  cvt(Wo, wob, 524288);
  cvt(W1, w1b, 2097152);
  cvt(W2, w2b, 2097152);
  cvt(Ew, ewb, 1048576);

  for (int l = 0; l < L_; ++l) {
    const u16* wq = wqb + (long)l * 262144;
    const u16* wk = wkb + (long)l * 262144;
    const u16* wv = wvb + (long)l * 262144;
    const u16* wo = wob + (long)l * 262144;
    const u16* w1 = w1b + (long)l * 1048576;
    const u16* w2 = w2b + (long)l * 1048576;

    // ---- phase A: shared E-projection xE = (Ew . x) once ----
    u16* xT = BIG;                                  // [B,C,N] 16MB
    float* partF = (float*)(BIG + 8388608);         // split-K partials 16MB
    transpose_kernel<<<dim3(64, 8, 4), dim3(256), 0, stream>>>(xb, xT);
    // xE[b,k,c] = Ew[k,:] . xT[b,c,:]  (split-K=8 over n; z=b)
    gemm_nt<128, 128, 7, 8><<<dim3(2, 4, 32), dim3(256), 0, stream>>>(
        ewb, xT, partF, nullptr, 4096, 4096, 4096, 512,
        0, 0, 0, 2097152, 0, 131072, 524288, 4, 1.f);
    reduce8_kernel<<<dim3(512), dim3(256), 0, stream>>>(partF, xEb);
    // Kp[b,k,hd] = xE . Wk^T + Eb[k]
    gemm_nt<128, 128, 4, 1><<<dim3(2, 4, 4), dim3(256), 0, stream>>>(
        xEb, wk, Kpb, Eb, 512, 512, 512, 512,
        0, 131072, 0, 0, 0, 131072, 0, 4, 1.f);
    // Vp^T[b,hd,k] = (xE . Wv^T)^T + Eb[k]
    gemm_nt<128, 128, 6, 1><<<dim3(2, 4, 4), dim3(256), 0, stream>>>(
        xEb, wv, Vpt, Eb, 512, 512, 512, 256,
        0, 131072, 0, 0, 0, 131072, 0, 4, 1.f);
    // Q = x @ Wq^T -> [B,N,H*D]
    gemm_nt<128, 128, 3, 1><<<dim3(128, 4, 1), dim3(256), 0, stream>>>(
        xb, wq, Qb, nullptr, 512, 512, 512, 512,
        0, 0, 0, 0, 0, 0, 0, 1, 1.f);

    // ---- phase B: attention in two half-batches (P = 32MB in BIG) ----
    for (int hf = 0; hf < 2; ++hf) {
      u16* Ph = BIG;
      const u16* Qh = Qb + (long)hf * 2 * 2097152;
      const u16* Kph = Kpb + (long)hf * 2 * 131072;
      const u16* Vph = Vpt + (long)hf * 2 * 131072;
      // S[b,h,n,k] = (Q_bh . Kp_bh) * 0.125  (z = b*8+h, b in half)
      gemm_nt<128, 128, 1, 1><<<dim3(32, 2, 16), dim3(256), 0, stream>>>(
          Qh, Kph, Ph, nullptr, 64, 512, 512, 256,
          2097152, 64, 131072, 64, 8388608, 1048576, 0, 16, 0.125f);
      softmax_kernel<<<dim3(16384), dim3(256), 0, stream>>>(Ph);
      // o[n,h*64+d] = P_bh . Vp^T_bh
      gemm_nt<128, 64, 1, 1><<<dim3(32, 1, 16), dim3(256), 0, stream>>>(
          Ph, Vph, Ob + (long)hf * 2 * 2097152, nullptr, 256, 256, 256, 512,
          8388608, 1048576, 131072, 16384, 2097152, 64, 0, 16, 1.f);
    }

    // y = o @ Wo^T + bo -> bf16 yb
    gemm_nt<128, 128, 3, 1><<<dim3(128, 4, 1), dim3(256), 0, stream>>>(
        Ob, wo, yb, bo + (long)l * 512, 512, 512, 512, 512,
        0, 0, 0, 0, 0, 0, 0, 1, 1.f);
    // x = LN(x + y) -> xb (bf16 residual stream)
    add_ln_kernel<<<dim3(4096), dim3(256), 0, stream>>>(
        l == 0 ? x : nullptr, l == 0 ? nullptr : xb, yb,
        ln1g + (long)l * 512, ln1b + (long)l * 512, nullptr, xb);

    // ---- phase C: FFN in 2 chunks of 8192 rows (h1 = 32MB in BIG) ----
    for (int ch = 0; ch < 2; ++ch) {
      u16* h1 = BIG;
      const u16* xch = xb + (long)ch * 4194304;
      // h1 = gelu(x @ W1^T + b1)
      gemm_nt<128, 128, 2, 1><<<dim3(64, 16, 1), dim3(256), 0, stream>>>(
          xch, w1, h1, b1 + (long)l * 2048, 512, 512, 512, 2048,
          0, 0, 0, 0, 0, 0, 0, 1, 1.f);
      // y = h1 @ W2^T + b2  (BN=64 -> grid (64,8) = 512 blocks)
      gemm_nt<128, 64, 3, 1><<<dim3(64, 8, 1), dim3(256), 0, stream>>>(
          h1, w2, yb + (long)ch * 4194304, b2 + (long)l * 512,
          2048, 2048, 2048, 512, 0, 0, 0, 0, 0, 0, 0, 1, 1.f);
    }
    // x = LN(x + y); final layer writes f32 d_out only
    add_ln_kernel<<<dim3(4096), dim3(256), 0, stream>>>(
        nullptr, xb, yb, ln2g + (long)l * 512, ln2b + (long)l * 512,
        (l == L_ - 1) ? xc : nullptr, (l == L_ - 1) ? (u16*)nullptr : xb);
  }
}

// Round 5
// 635.306 us; speedup vs baseline: 2.4267x; 1.1327x over previous
//
#include <hip/hip_runtime.h>
#include <math.h>

typedef unsigned short u16;
typedef __attribute__((ext_vector_type(8))) short short8;
typedef __attribute__((ext_vector_type(4))) float f32x4;

#define B_ 4
#define N_ 4096
#define C_ 512
#define H_ 8
#define D_ 64
#define KD_ 256
#define FF_ 2048
#define L_ 2

__device__ __forceinline__ float bf2f(u16 x) {
  return __builtin_bit_cast(float, (unsigned int)x << 16);
}
__device__ __forceinline__ u16 f2bf(float f) {
  unsigned int t = __builtin_bit_cast(unsigned int, f);
  return (u16)((t + 0x7fffu + ((t >> 16) & 1u)) >> 16);
}

// async global->LDS, 16B per lane
#define GLD(g, l)                                                             \
  __builtin_amdgcn_global_load_lds(                                           \
      (const __attribute__((address_space(1))) void*)(g),                     \
      (__attribute__((address_space(3))) void*)(l), 16, 0, 0)

// ---------------- f32 -> bf16 convert ----------------
__global__ __launch_bounds__(256) void cvt_kernel(const float* __restrict__ in,
                                                  u16* __restrict__ out, int n4) {
  int i = blockIdx.x * 256 + threadIdx.x;
  if (i >= n4) return;
  float4 v = reinterpret_cast<const float4*>(in)[i];
  ushort4 o;
  o.x = f2bf(v.x); o.y = f2bf(v.y); o.z = f2bf(v.z); o.w = f2bf(v.w);
  reinterpret_cast<ushort4*>(out)[i] = o;
}

// ---------------- bf16 transpose [B,N,C] -> [B,C,N], 64x64 tiles ----------------
__global__ __launch_bounds__(256) void transpose_kernel(const u16* __restrict__ in,
                                                        u16* __restrict__ out) {
  __shared__ u16 T[64][72];
  int n0 = blockIdx.x * 64, c0 = blockIdx.y * 64, b = blockIdx.z;
  const u16* src = in + (long)b * N_ * C_;
  u16* dst = out + (long)b * C_ * N_;
  int t = threadIdx.x;
  int r = t >> 3, cq = (t & 7) * 8;
#pragma unroll
  for (int h = 0; h < 2; ++h) {
    const u16* p = src + (long)(n0 + r + h * 32) * C_ + c0 + cq;
    ushort4 v0 = *reinterpret_cast<const ushort4*>(p);
    ushort4 v1 = *reinterpret_cast<const ushort4*>(p + 4);
    T[r + h * 32][cq + 0] = v0.x; T[r + h * 32][cq + 1] = v0.y;
    T[r + h * 32][cq + 2] = v0.z; T[r + h * 32][cq + 3] = v0.w;
    T[r + h * 32][cq + 4] = v1.x; T[r + h * 32][cq + 5] = v1.y;
    T[r + h * 32][cq + 6] = v1.z; T[r + h * 32][cq + 7] = v1.w;
  }
  __syncthreads();
  int cc = t >> 3, nq = (t & 7) * 8;
#pragma unroll
  for (int h = 0; h < 2; ++h) {
    int cl = cc + h * 32;
    ushort4 w0, w1;
    w0.x = T[nq + 0][cl]; w0.y = T[nq + 1][cl];
    w0.z = T[nq + 2][cl]; w0.w = T[nq + 3][cl];
    w1.x = T[nq + 4][cl]; w1.y = T[nq + 5][cl];
    w1.z = T[nq + 6][cl]; w1.w = T[nq + 7][cl];
    u16* q = dst + (long)(c0 + cl) * N_ + n0 + nq;
    *reinterpret_cast<ushort4*>(q) = w0;
    *reinterpret_cast<ushort4*>(q + 4) = w1;
  }
}

// ---------------- generic NT MFMA GEMM (global_load_lds staging) ----------------
// C[m,j] = sum_k A[m,k]*B[j,k]; two-level z batch (zb=z>>3, zh=z&7); split-K sCh.
// EPI: 2 bf16 gelu(v+bias[j]) | 3 bf16 +bias[j](nullable) | 4 bf16 +bias[m]
//      6 bf16 transposed store [j,m] +bias[m] | 7 f32 partial
template <int BM, int BN, int EPI, int SPLITK>
__global__ __launch_bounds__(256, 2) void gemm_nt(
    const u16* __restrict__ A, const u16* __restrict__ B, void* __restrict__ Cout,
    const float* __restrict__ bias, int K, int lda, int ldb, int ldc,
    long sA0, long sA1, long sB0, long sB1, long sC0, long sC1, long sCh,
    int nz, float alpha) {
  constexpr int BK = 64;
  constexpr int WM = BM / 2, WN = BN / 2;
  constexpr int FM = WM / 16, FN = WN / 16;
  constexpr int CA = BM / 32, CB = BN / 32;  // 16B lds-loads per thread

  __shared__ __attribute__((aligned(16))) u16 As[BM * BK];
  __shared__ __attribute__((aligned(16))) u16 Bs[BN * BK];

  int z, chunk;
  if constexpr (SPLITK > 1) { z = blockIdx.z % nz; chunk = blockIdx.z / nz; }
  else { z = blockIdx.z; chunk = 0; }
  int zb = z >> 3, zh = z & 7;
  A += (long)zb * sA0 + (long)zh * sA1;
  B += (long)zb * sB0 + (long)zh * sB1;
  long coff = (long)zb * sC0 + (long)zh * sC1 + (long)chunk * sCh;

  int tid = threadIdx.x;
  int lane = tid & 63, wid = tid >> 6;
  int wr = wid >> 1, wc = wid & 1;
  int row0 = blockIdx.x * BM, col0 = blockIdx.y * BN;

  int Kc = K / SPLITK;
  int kbeg = chunk * Kc;

  f32x4 acc[FM][FN] = {};

  for (int k0 = kbeg; k0 < kbeg + Kc; k0 += BK) {
#pragma unroll
    for (int i = 0; i < CA; ++i) {
      int c = tid + i * 256;
      GLD(A + (long)(row0 + (c >> 3)) * lda + k0 + (c & 7) * 8, As + c * 8);
    }
#pragma unroll
    for (int i = 0; i < CB; ++i) {
      int c = tid + i * 256;
      GLD(B + (long)(col0 + (c >> 3)) * ldb + k0 + (c & 7) * 8, Bs + c * 8);
    }
    __syncthreads();

    int lr = lane & 15, lk = (lane >> 4) * 8;
#pragma unroll
    for (int kk = 0; kk < BK; kk += 32) {
      short8 af[FM], bfr[FN];
#pragma unroll
      for (int mi = 0; mi < FM; ++mi)
        af[mi] = *reinterpret_cast<const short8*>(&As[(wr * WM + mi * 16 + lr) * BK + kk + lk]);
#pragma unroll
      for (int nj = 0; nj < FN; ++nj)
        bfr[nj] = *reinterpret_cast<const short8*>(&Bs[(wc * WN + nj * 16 + lr) * BK + kk + lk]);
#pragma unroll
      for (int mi = 0; mi < FM; ++mi)
#pragma unroll
        for (int nj = 0; nj < FN; ++nj)
          acc[mi][nj] = __builtin_amdgcn_mfma_f32_16x16x32_bf16(af[mi], bfr[nj], acc[mi][nj], 0, 0, 0);
    }
    __syncthreads();
  }

  // epilogue: C/D layout col=lane&15, row=(lane>>4)*4+reg
  int lc = lane & 15, rb = (lane >> 4) * 4;
#pragma unroll
  for (int mi = 0; mi < FM; ++mi) {
#pragma unroll
    for (int nj = 0; nj < FN; ++nj) {
      int j = col0 + wc * WN + nj * 16 + lc;
      int m0 = row0 + wr * WM + mi * 16 + rb;
#pragma unroll
      for (int r = 0; r < 4; ++r) {
        int m = m0 + r;
        float v = acc[mi][nj][r];
        if constexpr (EPI == 2) {
          float t = v + bias[j];
          float gl = 0.5f * t * (1.f + erff(t * 0.70710678118f));
          reinterpret_cast<u16*>(Cout)[coff + (long)m * ldc + j] = f2bf(gl);
        } else if constexpr (EPI == 3) {
          float bi = bias ? bias[j] : 0.f;
          reinterpret_cast<u16*>(Cout)[coff + (long)m * ldc + j] = f2bf(v + bi);
        } else if constexpr (EPI == 4) {
          reinterpret_cast<u16*>(Cout)[coff + (long)m * ldc + j] = f2bf(v + bias[m]);
        } else if constexpr (EPI == 6) {
          reinterpret_cast<u16*>(Cout)[coff + (long)j * ldc + m] = f2bf(v + bias[m]);
        } else {  // 7: f32 split-K partial
          reinterpret_cast<float*>(Cout)[coff + (long)m * ldc + j] = v;
        }
      }
    }
  }
}

// ---------------- split-K reduce: sum 8 f32 chunks -> bf16 ----------------
__global__ __launch_bounds__(256) void reduce8_kernel(const float* __restrict__ part,
                                                      u16* __restrict__ out) {
  int i = blockIdx.x * 256 + threadIdx.x;  // float4 index, 131072 total
  const float4* p = reinterpret_cast<const float4*>(part);
  float4 s = p[i];
#pragma unroll
  for (int c = 1; c < 8; ++c) {
    float4 t = p[i + c * 131072];
    s.x += t.x; s.y += t.y; s.z += t.z; s.w += t.w;
  }
  ushort4 o;
  o.x = f2bf(s.x); o.y = f2bf(s.y); o.z = f2bf(s.z); o.w = f2bf(s.w);
  reinterpret_cast<ushort4*>(out)[i] = o;
}

// ---------------- fused attention: S=Q.Kp^T, softmax, O=P.Vp ----------------
// grid (N/128, B*H); 512 threads = 8 waves; per wave: 16 q-rows.
// Q [B,N,512] (head cols h*64..), Kp [B,256,512], Vpt [B,512,256]. O aliases Q.
__global__ __launch_bounds__(512, 2) void attn_kernel(
    const u16* __restrict__ Q, const u16* __restrict__ Kp,
    const u16* __restrict__ Vpt, u16* __restrict__ O) {
  constexpr int LQ = 72, LKP = 72, LVP = 264, LP = 264;
  __shared__ __attribute__((aligned(16))) u16 Q_s[128 * LQ];    // 18.4 KB
  __shared__ __attribute__((aligned(16))) u16 Kp_s[256 * LKP];  // 36.9 KB
  __shared__ __attribute__((aligned(16))) u16 Vp_s[64 * LVP];   // 33.8 KB
  __shared__ __attribute__((aligned(16))) u16 P_s[128 * LP];    // 67.6 KB

  int n0 = blockIdx.x * 128;
  int bh = blockIdx.y;
  int b = bh >> 3, h = bh & 7;
  long qbase = ((long)b * N_ + n0) * 512 + h * 64;
  const u16* Kpb = Kp + ((long)b * KD_) * 512 + h * 64;
  const u16* Vpb = Vpt + ((long)b * 512 + h * 64) * KD_;

  int tid = threadIdx.x;
  // stage Q: 128x64 (2 iters), Kp: 256x64 (4 iters), Vp: 64x256 (4 iters)
#pragma unroll
  for (int i = 0; i < 2; ++i) {
    int c = tid + i * 512;
    int r = c >> 3, c8 = (c & 7) * 8;
    *reinterpret_cast<uint4*>(&Q_s[r * LQ + c8]) =
        *reinterpret_cast<const uint4*>(Q + qbase + (long)r * 512 + c8);
  }
#pragma unroll
  for (int i = 0; i < 4; ++i) {
    int c = tid + i * 512;
    int r = c >> 3, c8 = (c & 7) * 8;
    *reinterpret_cast<uint4*>(&Kp_s[r * LKP + c8]) =
        *reinterpret_cast<const uint4*>(Kpb + (long)r * 512 + c8);
  }
#pragma unroll
  for (int i = 0; i < 4; ++i) {
    int c = tid + i * 512;
    int r = c >> 5, c8 = (c & 31) * 8;
    *reinterpret_cast<uint4*>(&Vp_s[r * LVP + c8]) =
        *reinterpret_cast<const uint4*>(Vpb + (long)r * KD_ + c8);
  }
  __syncthreads();

  int lane = tid & 63, w = tid >> 6;
  int q0 = w * 16;
  int lr = lane & 15, lk = (lane >> 4) * 8;
  int lc = lane & 15, rb = (lane >> 4) * 4;

  // ---- S = Q . Kp^T (per wave: 16 rows x 256 cols = 16 tiles) ----
  f32x4 acc[16] = {};
  short8 af0 = *reinterpret_cast<const short8*>(&Q_s[(q0 + lr) * LQ + lk]);
  short8 af1 = *reinterpret_cast<const short8*>(&Q_s[(q0 + lr) * LQ + 32 + lk]);
#pragma unroll
  for (int t = 0; t < 16; ++t) {
    short8 b0 = *reinterpret_cast<const short8*>(&Kp_s[(t * 16 + lr) * LKP + lk]);
    short8 b1 = *reinterpret_cast<const short8*>(&Kp_s[(t * 16 + lr) * LKP + 32 + lk]);
    acc[t] = __builtin_amdgcn_mfma_f32_16x16x32_bf16(af0, b0, acc[t], 0, 0, 0);
    acc[t] = __builtin_amdgcn_mfma_f32_16x16x32_bf16(af1, b1, acc[t], 0, 0, 0);
  }

  // ---- softmax over k=256 (rows lane-local across 16 tiles + lane&15 groups) ----
  float mx[4] = {-3.4e38f, -3.4e38f, -3.4e38f, -3.4e38f};
#pragma unroll
  for (int t = 0; t < 16; ++t)
#pragma unroll
    for (int r = 0; r < 4; ++r) {
      acc[t][r] *= 0.125f;
      mx[r] = fmaxf(mx[r], acc[t][r]);
    }
#pragma unroll
  for (int o = 1; o < 16; o <<= 1)
#pragma unroll
    for (int r = 0; r < 4; ++r) mx[r] = fmaxf(mx[r], __shfl_xor(mx[r], o));
  float sm[4] = {0.f, 0.f, 0.f, 0.f};
#pragma unroll
  for (int t = 0; t < 16; ++t)
#pragma unroll
    for (int r = 0; r < 4; ++r) {
      float e = __expf(acc[t][r] - mx[r]);
      acc[t][r] = e;
      sm[r] += e;
    }
#pragma unroll
  for (int o = 1; o < 16; o <<= 1)
#pragma unroll
    for (int r = 0; r < 4; ++r) sm[r] += __shfl_xor(sm[r], o);
  float inv[4];
#pragma unroll
  for (int r = 0; r < 4; ++r) inv[r] = 1.f / sm[r];
  // P -> LDS bf16 (wave-private rows; no barrier needed before PV)
#pragma unroll
  for (int t = 0; t < 16; ++t)
#pragma unroll
    for (int r = 0; r < 4; ++r)
      P_s[(q0 + rb + r) * LP + t * 16 + lc] = f2bf(acc[t][r] * inv[r]);

  // ---- O = P . Vp (16 rows x 64 cols = 4 tiles, K=256) ----
  f32x4 o2[4] = {};
#pragma unroll
  for (int kk = 0; kk < 8; ++kk) {
    short8 pa = *reinterpret_cast<const short8*>(&P_s[(q0 + lr) * LP + kk * 32 + lk]);
#pragma unroll
    for (int nj = 0; nj < 4; ++nj) {
      short8 vb = *reinterpret_cast<const short8*>(&Vp_s[(nj * 16 + lr) * LVP + kk * 32 + lk]);
      o2[nj] = __builtin_amdgcn_mfma_f32_16x16x32_bf16(pa, vb, o2[nj], 0, 0, 0);
    }
  }
#pragma unroll
  for (int nj = 0; nj < 4; ++nj)
#pragma unroll
    for (int r = 0; r < 4; ++r)
      O[qbase + (long)(q0 + rb + r) * 512 + nj * 16 + lc] = f2bf(o2[nj][r]);
}

// ---------------- residual add + LayerNorm (row of 512), bf16 residual stream --------
__global__ __launch_bounds__(256) void add_ln_kernel(
    const float* __restrict__ xin32, const u16* __restrict__ xinb,
    const u16* __restrict__ yin, const float* __restrict__ g,
    const float* __restrict__ bt, float* __restrict__ xout32,
    u16* __restrict__ xbout) {
  int row = blockIdx.x * 4 + (threadIdx.x >> 6);
  int lane = threadIdx.x & 63;
  long base = (long)row * C_ + lane * 8;
  float s[8];
  if (xin32) {
    float4 a0 = *reinterpret_cast<const float4*>(xin32 + base);
    float4 a1 = *reinterpret_cast<const float4*>(xin32 + base + 4);
    s[0] = a0.x; s[1] = a0.y; s[2] = a0.z; s[3] = a0.w;
    s[4] = a1.x; s[5] = a1.y; s[6] = a1.z; s[7] = a1.w;
  } else {
    ushort4 x0 = *reinterpret_cast<const ushort4*>(xinb + base);
    ushort4 x1 = *reinterpret_cast<const ushort4*>(xinb + base + 4);
    s[0] = bf2f(x0.x); s[1] = bf2f(x0.y); s[2] = bf2f(x0.z); s[3] = bf2f(x0.w);
    s[4] = bf2f(x1.x); s[5] = bf2f(x1.y); s[6] = bf2f(x1.z); s[7] = bf2f(x1.w);
  }
  ushort4 u0 = *reinterpret_cast<const ushort4*>(yin + base);
  ushort4 u1 = *reinterpret_cast<const ushort4*>(yin + base + 4);
  s[0] += bf2f(u0.x); s[1] += bf2f(u0.y); s[2] += bf2f(u0.z); s[3] += bf2f(u0.w);
  s[4] += bf2f(u1.x); s[5] += bf2f(u1.y); s[6] += bf2f(u1.z); s[7] += bf2f(u1.w);
  float sum = 0.f;
#pragma unroll
  for (int i = 0; i < 8; ++i) sum += s[i];
#pragma unroll
  for (int o = 1; o < 64; o <<= 1) sum += __shfl_xor(sum, o);
  float mean = sum * (1.f / C_);
  float var = 0.f;
#pragma unroll
  for (int i = 0; i < 8; ++i) { float d = s[i] - mean; var += d * d; }
#pragma unroll
  for (int o = 1; o < 64; o <<= 1) var += __shfl_xor(var, o);
  float inv = rsqrtf(var * (1.f / C_) + 1e-5f);
  int c0 = lane * 8;
  float o[8];
#pragma unroll
  for (int i = 0; i < 8; ++i) o[i] = (s[i] - mean) * inv * g[c0 + i] + bt[c0 + i];
  if (xout32) {
    float4 f0 = {o[0], o[1], o[2], o[3]};
    float4 f1 = {o[4], o[5], o[6], o[7]};
    *reinterpret_cast<float4*>(xout32 + base) = f0;
    *reinterpret_cast<float4*>(xout32 + base + 4) = f1;
  }
  if (xbout) {
    ushort4 w0 = {f2bf(o[0]), f2bf(o[1]), f2bf(o[2]), f2bf(o[3])};
    ushort4 w1 = {f2bf(o[4]), f2bf(o[5]), f2bf(o[6]), f2bf(o[7])};
    *reinterpret_cast<ushort4*>(xbout + base) = w0;
    *reinterpret_cast<ushort4*>(xbout + base + 4) = w1;
  }
}

extern "C" void kernel_launch(void* const* d_in, const int* in_sizes, int n_in,
                              void* d_out, int out_size, void* d_ws, size_t ws_size,
                              hipStream_t stream) {
  const float* x    = (const float*)d_in[0];
  const float* Wq   = (const float*)d_in[1];
  const float* Wk   = (const float*)d_in[2];
  const float* Wv   = (const float*)d_in[3];
  const float* Wo   = (const float*)d_in[4];
  const float* bo   = (const float*)d_in[5];
  const float* ln1g = (const float*)d_in[6];
  const float* ln1b = (const float*)d_in[7];
  const float* W1   = (const float*)d_in[8];
  const float* b1   = (const float*)d_in[9];
  const float* W2   = (const float*)d_in[10];
  const float* b2   = (const float*)d_in[11];
  const float* ln2g = (const float*)d_in[12];
  const float* ln2b = (const float*)d_in[13];
  const float* Ew   = (const float*)d_in[14];
  const float* Eb   = (const float*)d_in[15];
  float* xc = (float*)d_out;  // final f32 output only

  // workspace ~97 MB, write-before-read every call
  char* wsp = (char*)d_ws;
  size_t off = 0;
  auto alloc = [&](size_t bytes) -> void* {
    void* p = wsp + off;
    off = (off + bytes + 255) & ~(size_t)255;
    return p;
  };
  u16* xb  = (u16*)alloc(8388608UL * 2);   // x bf16 [B,N,C]
  u16* BIG = (u16*)alloc(16777216UL * 2);  // 32MB: xT+xE-partials | h1 chunk
  u16* Qb  = (u16*)alloc(8388608UL * 2);   // Q [B,N,H*D]; attn-out aliases in place
  u16* yb  = (u16*)alloc(8388608UL * 2);   // y bf16 [B,N,C]
  u16* xEb = (u16*)alloc(524288UL * 2);    // xE bf16 [B,KD,C]
  u16* Kpb = (u16*)alloc(524288UL * 2);    // Kp [B,KD,H*D]
  u16* Vpt = (u16*)alloc(524288UL * 2);    // Vp^T [B,H*D,KD]
  u16* wqb = (u16*)alloc(524288UL * 2);
  u16* wkb = (u16*)alloc(524288UL * 2);
  u16* wvb = (u16*)alloc(524288UL * 2);
  u16* wob = (u16*)alloc(524288UL * 2);
  u16* w1b = (u16*)alloc(2097152UL * 2);
  u16* w2b = (u16*)alloc(2097152UL * 2);
  u16* ewb = (u16*)alloc(1048576UL * 2);
  (void)ws_size; (void)in_sizes; (void)n_in; (void)out_size;

  auto cvt = [&](const float* src, u16* dst, long n) {
    int n4 = (int)(n / 4);
    cvt_kernel<<<dim3((n4 + 255) / 256), dim3(256), 0, stream>>>(src, dst, n4);
  };
  cvt(x, xb, 8388608);
  cvt(Wq, wqb, 524288);
  cvt(Wk, wkb, 524288);
  cvt(Wv, wvb, 524288);
  cvt(Wo, wob, 524288);
  cvt(W1, w1b, 2097152);
  cvt(W2, w2b, 2097152);
  cvt(Ew, ewb, 1048576);

  for (int l = 0; l < L_; ++l) {
    const u16* wq = wqb + (long)l * 262144;
    const u16* wk = wkb + (long)l * 262144;
    const u16* wv = wvb + (long)l * 262144;
    const u16* wo = wob + (long)l * 262144;
    const u16* w1 = w1b + (long)l * 1048576;
    const u16* w2 = w2b + (long)l * 1048576;

    // ---- phase A: shared E-projection xE = (Ew . x) once ----
    u16* xT = BIG;                           // [B,C,N] 16MB
    float* partF = (float*)(BIG + 8388608);  // split-K partials 16MB
    transpose_kernel<<<dim3(64, 8, 4), dim3(256), 0, stream>>>(xb, xT);
    gemm_nt<128, 128, 7, 8><<<dim3(2, 4, 32), dim3(256), 0, stream>>>(
        ewb, xT, partF, nullptr, 4096, 4096, 4096, 512,
        0, 0, 0, 2097152, 0, 131072, 524288, 4, 1.f);
    reduce8_kernel<<<dim3(512), dim3(256), 0, stream>>>(partF, xEb);
    // Kp[b,k,hd] = xE . Wk^T + Eb[k]
    gemm_nt<128, 128, 4, 1><<<dim3(2, 4, 4), dim3(256), 0, stream>>>(
        xEb, wk, Kpb, Eb, 512, 512, 512, 512,
        0, 131072, 0, 0, 0, 131072, 0, 4, 1.f);
    // Vp^T[b,hd,k] = (xE . Wv^T)^T + Eb[k]
    gemm_nt<128, 128, 6, 1><<<dim3(2, 4, 4), dim3(256), 0, stream>>>(
        xEb, wv, Vpt, Eb, 512, 512, 512, 256,
        0, 131072, 0, 0, 0, 131072, 0, 4, 1.f);
    // Q = x @ Wq^T -> [B,N,H*D]
    gemm_nt<128, 128, 3, 1><<<dim3(128, 4, 1), dim3(256), 0, stream>>>(
        xb, wq, Qb, nullptr, 512, 512, 512, 512,
        0, 0, 0, 0, 0, 0, 0, 1, 1.f);

    // ---- phase B: fused attention (S, softmax, PV all in-LDS/regs) ----
    attn_kernel<<<dim3(32, 32), dim3(512), 0, stream>>>(Qb, Kpb, Vpt, Qb);

    // y = o @ Wo^T + bo -> bf16 yb
    gemm_nt<128, 128, 3, 1><<<dim3(128, 4, 1), dim3(256), 0, stream>>>(
        Qb, wo, yb, bo + (long)l * 512, 512, 512, 512, 512,
        0, 0, 0, 0, 0, 0, 0, 1, 1.f);
    // x = LN(x + y) -> xb (bf16 residual stream)
    add_ln_kernel<<<dim3(4096), dim3(256), 0, stream>>>(
        l == 0 ? x : nullptr, l == 0 ? nullptr : xb, yb,
        ln1g + (long)l * 512, ln1b + (long)l * 512, nullptr, xb);

    // ---- phase C: FFN in 2 chunks of 8192 rows (h1 = 32MB in BIG) ----
    for (int ch = 0; ch < 2; ++ch) {
      u16* h1 = BIG;
      const u16* xch = xb + (long)ch * 4194304;
      gemm_nt<128, 128, 2, 1><<<dim3(64, 16, 1), dim3(256), 0, stream>>>(
          xch, w1, h1, b1 + (long)l * 2048, 512, 512, 512, 2048,
          0, 0, 0, 0, 0, 0, 0, 1, 1.f);
      gemm_nt<128, 64, 3, 1><<<dim3(64, 8, 1), dim3(256), 0, stream>>>(
          h1, w2, yb + (long)ch * 4194304, b2 + (long)l * 512,
          2048, 2048, 2048, 512, 0, 0, 0, 0, 0, 0, 0, 1, 1.f);
    }
    // x = LN(x + y); final layer writes f32 d_out only
    add_ln_kernel<<<dim3(4096), dim3(256), 0, stream>>>(
        nullptr, xb, yb, ln2g + (long)l * 512, ln2b + (long)l * 512,
        (l == L_ - 1) ? xc : nullptr, (l == L_ - 1) ? (u16*)nullptr : xb);
  }
}

// Round 6
// 626.464 us; speedup vs baseline: 2.4609x; 1.0141x over previous
//
#include <hip/hip_runtime.h>
#include <math.h>

typedef unsigned short u16;
typedef __attribute__((ext_vector_type(8))) short short8;
typedef __attribute__((ext_vector_type(4))) float f32x4;

#define B_ 4
#define N_ 4096
#define C_ 512
#define H_ 8
#define D_ 64
#define KD_ 256
#define FF_ 2048
#define L_ 2

__device__ __forceinline__ float bf2f(u16 x) {
  return __builtin_bit_cast(float, (unsigned int)x << 16);
}
__device__ __forceinline__ u16 f2bf(float f) {
  unsigned int t = __builtin_bit_cast(unsigned int, f);
  return (u16)((t + 0x7fffu + ((t >> 16) & 1u)) >> 16);
}

// async global->LDS, 16B per lane
#define GLD(g, l)                                                             \
  __builtin_amdgcn_global_load_lds(                                           \
      (const __attribute__((address_space(1))) void*)(g),                     \
      (__attribute__((address_space(3))) void*)(l), 16, 0, 0)

#define MFMA16 __builtin_amdgcn_mfma_f32_16x16x32_bf16

// ---------------- f32 -> bf16 convert ----------------
__global__ __launch_bounds__(256) void cvt_kernel(const float* __restrict__ in,
                                                  u16* __restrict__ out, int n4) {
  int i = blockIdx.x * 256 + threadIdx.x;
  if (i >= n4) return;
  float4 v = reinterpret_cast<const float4*>(in)[i];
  ushort4 o;
  o.x = f2bf(v.x); o.y = f2bf(v.y); o.z = f2bf(v.z); o.w = f2bf(v.w);
  reinterpret_cast<ushort4*>(out)[i] = o;
}

// ---------------- bf16 transpose [B,N,C] -> [B,C,N], 64x64 tiles ----------------
__global__ __launch_bounds__(256) void transpose_kernel(const u16* __restrict__ in,
                                                        u16* __restrict__ out) {
  __shared__ u16 T[64][72];
  int n0 = blockIdx.x * 64, c0 = blockIdx.y * 64, b = blockIdx.z;
  const u16* src = in + (long)b * N_ * C_;
  u16* dst = out + (long)b * C_ * N_;
  int t = threadIdx.x;
  int r = t >> 3, cq = (t & 7) * 8;
#pragma unroll
  for (int h = 0; h < 2; ++h) {
    const u16* p = src + (long)(n0 + r + h * 32) * C_ + c0 + cq;
    ushort4 v0 = *reinterpret_cast<const ushort4*>(p);
    ushort4 v1 = *reinterpret_cast<const ushort4*>(p + 4);
    T[r + h * 32][cq + 0] = v0.x; T[r + h * 32][cq + 1] = v0.y;
    T[r + h * 32][cq + 2] = v0.z; T[r + h * 32][cq + 3] = v0.w;
    T[r + h * 32][cq + 4] = v1.x; T[r + h * 32][cq + 5] = v1.y;
    T[r + h * 32][cq + 6] = v1.z; T[r + h * 32][cq + 7] = v1.w;
  }
  __syncthreads();
  int cc = t >> 3, nq = (t & 7) * 8;
#pragma unroll
  for (int h = 0; h < 2; ++h) {
    int cl = cc + h * 32;
    ushort4 w0, w1;
    w0.x = T[nq + 0][cl]; w0.y = T[nq + 1][cl];
    w0.z = T[nq + 2][cl]; w0.w = T[nq + 3][cl];
    w1.x = T[nq + 4][cl]; w1.y = T[nq + 5][cl];
    w1.z = T[nq + 6][cl]; w1.w = T[nq + 7][cl];
    u16* q = dst + (long)(c0 + cl) * N_ + n0 + nq;
    *reinterpret_cast<ushort4*>(q) = w0;
    *reinterpret_cast<ushort4*>(q + 4) = w1;
  }
}

// ---------------- 256x256 phase-split MFMA GEMM (NT) ----------------
// C[m,j] = sum_k A[m,k]*B[j,k]. 512 thr = 8 waves (2x4), per-wave 128x64 out.
// Double-buffered 128KB LDS, global_load_lds staging, raw s_barrier phases,
// setprio around MFMA clusters, XCD-chunked block swizzle (grid%8==0).
// EPI: 0 plain bf16 | 1 +bias[j] | 2 gelu(v+bias[j])
template <int EPI>
__global__ __launch_bounds__(512, 2) void gemm256_nt(
    const u16* __restrict__ A, const u16* __restrict__ B, u16* __restrict__ C,
    const float* __restrict__ bias, int K, int lda, int ldb, int ldc) {
  __shared__ __attribute__((aligned(16))) u16 As[2 * 16384];
  __shared__ __attribute__((aligned(16))) u16 Bs[2 * 16384];

  int gy = gridDim.y;
  int nwg = gridDim.x * gy;
  int id = blockIdx.x * gy + blockIdx.y;
  int q = nwg >> 3;
  int nid = (id & 7) * q + (id >> 3);  // XCD-chunked, bijective when nwg%8==0
  int row0 = (nid / gy) * 256, col0 = (nid % gy) * 256;

  int tid = threadIdx.x;
  int lane = tid & 63, wid = tid >> 6;
  int wr = wid >> 2, wc = wid & 3;  // 2 (M) x 4 (N) waves
  int lr = lane & 15, lk = (lane >> 4) * 8;

  int ar0 = tid >> 3, ac0 = (tid & 7) * 8;
  int f1 = tid + 512;
  int ar1 = f1 >> 3, ac1 = (f1 & 7) * 8;

  auto stageA = [&](int d, int h, int k0) {
    GLD(A + (long)(row0 + h * 128 + ar0) * lda + k0 + ac0,
        As + d * 16384 + h * 8192 + tid * 8);
    GLD(A + (long)(row0 + h * 128 + ar1) * lda + k0 + ac1,
        As + d * 16384 + h * 8192 + f1 * 8);
  };
  auto stageB = [&](int d, int h, int k0) {
    GLD(B + (long)(col0 + h * 128 + ar0) * ldb + k0 + ac0,
        Bs + d * 16384 + h * 8192 + tid * 8);
    GLD(B + (long)(col0 + h * 128 + ar1) * ldb + k0 + ac1,
        Bs + d * 16384 + h * 8192 + f1 * 8);
  };

  f32x4 acc[8][4] = {};
  int NT = K >> 6;

  // prologue: stage K-tile 0 into buffer 0
  stageA(0, 0, 0); stageA(0, 1, 0); stageB(0, 0, 0); stageB(0, 1, 0);

  for (int t = 0; t < NT; ++t) {
    int cur = t & 1, nxt = cur ^ 1;
    const u16* Ab = As + cur * 16384;
    const u16* Bb = Bs + cur * 16384;
    int k1 = (t + 1) << 6;
    bool pf = (t + 1 < NT);

    // tile-t handoff: my stage loads done, then all waves' (barrier)
    asm volatile("s_waitcnt vmcnt(0)" ::: "memory");
    __builtin_amdgcn_s_barrier();

    short8 bf0[4], bf1[4], af[4];
    // ---- phase 0: kk=0, mi 0..3 (reads B kk=0) ----
#pragma unroll
    for (int nj = 0; nj < 4; ++nj)
      bf0[nj] = *reinterpret_cast<const short8*>(&Bb[(wc * 64 + nj * 16 + lr) * 64 + lk]);
#pragma unroll
    for (int mi = 0; mi < 4; ++mi)
      af[mi] = *reinterpret_cast<const short8*>(&Ab[(wr * 128 + mi * 16 + lr) * 64 + lk]);
    if (pf) stageA(nxt, 0, k1);
    __builtin_amdgcn_s_barrier();
    __builtin_amdgcn_s_setprio(1);
#pragma unroll
    for (int mi = 0; mi < 4; ++mi)
#pragma unroll
      for (int nj = 0; nj < 4; ++nj)
        acc[mi][nj] = MFMA16(af[mi], bf0[nj], acc[mi][nj], 0, 0, 0);
    __builtin_amdgcn_s_setprio(0);
    __builtin_amdgcn_s_barrier();
    // ---- phase 1: kk=0, mi 4..7 (B reuse) ----
#pragma unroll
    for (int mi = 0; mi < 4; ++mi)
      af[mi] = *reinterpret_cast<const short8*>(&Ab[(wr * 128 + (mi + 4) * 16 + lr) * 64 + lk]);
    if (pf) stageA(nxt, 1, k1);
    __builtin_amdgcn_s_barrier();
    __builtin_amdgcn_s_setprio(1);
#pragma unroll
    for (int mi = 0; mi < 4; ++mi)
#pragma unroll
      for (int nj = 0; nj < 4; ++nj)
        acc[mi + 4][nj] = MFMA16(af[mi], bf0[nj], acc[mi + 4][nj], 0, 0, 0);
    __builtin_amdgcn_s_setprio(0);
    __builtin_amdgcn_s_barrier();
    // ---- phase 2: kk=32, mi 0..3 (reads B kk=32) ----
#pragma unroll
    for (int nj = 0; nj < 4; ++nj)
      bf1[nj] = *reinterpret_cast<const short8*>(&Bb[(wc * 64 + nj * 16 + lr) * 64 + 32 + lk]);
#pragma unroll
    for (int mi = 0; mi < 4; ++mi)
      af[mi] = *reinterpret_cast<const short8*>(&Ab[(wr * 128 + mi * 16 + lr) * 64 + 32 + lk]);
    if (pf) stageB(nxt, 0, k1);
    __builtin_amdgcn_s_barrier();
    __builtin_amdgcn_s_setprio(1);
#pragma unroll
    for (int mi = 0; mi < 4; ++mi)
#pragma unroll
      for (int nj = 0; nj < 4; ++nj)
        acc[mi][nj] = MFMA16(af[mi], bf1[nj], acc[mi][nj], 0, 0, 0);
    __builtin_amdgcn_s_setprio(0);
    __builtin_amdgcn_s_barrier();
    // ---- phase 3: kk=32, mi 4..7 ----
#pragma unroll
    for (int mi = 0; mi < 4; ++mi)
      af[mi] = *reinterpret_cast<const short8*>(&Ab[(wr * 128 + (mi + 4) * 16 + lr) * 64 + 32 + lk]);
    if (pf) stageB(nxt, 1, k1);
    __builtin_amdgcn_s_barrier();
    __builtin_amdgcn_s_setprio(1);
#pragma unroll
    for (int mi = 0; mi < 4; ++mi)
#pragma unroll
      for (int nj = 0; nj < 4; ++nj)
        acc[mi + 4][nj] = MFMA16(af[mi], bf1[nj], acc[mi + 4][nj], 0, 0, 0);
    __builtin_amdgcn_s_setprio(0);
    __builtin_amdgcn_s_barrier();
  }

  // epilogue: C/D layout col=lane&15, row=(lane>>4)*4+reg
  int lc = lane & 15, rb = (lane >> 4) * 4;
#pragma unroll
  for (int mi = 0; mi < 8; ++mi) {
#pragma unroll
    for (int nj = 0; nj < 4; ++nj) {
      int j = col0 + wc * 64 + nj * 16 + lc;
      int m0 = row0 + wr * 128 + mi * 16 + rb;
#pragma unroll
      for (int r = 0; r < 4; ++r) {
        int m = m0 + r;
        float v = acc[mi][nj][r];
        if constexpr (EPI == 0) {
          C[(long)m * ldc + j] = f2bf(v);
        } else if constexpr (EPI == 1) {
          C[(long)m * ldc + j] = f2bf(v + bias[j]);
        } else {  // 2: fast tanh-GELU (max dev from erf-gelu ~3e-3)
          float tt = v + bias[j];
          float u = tt * (0.7978845608f + 0.0356774081f * tt * tt);
          float e = __expf(2.f * u);
          float th = 1.f - 2.f / (e + 1.f);
          C[(long)m * ldc + j] = f2bf(0.5f * tt * (1.f + th));
        }
      }
    }
  }
}

// ---------------- generic 128-tile NT MFMA GEMM (global_load_lds staging) --------
// C[m,j] = sum_k A[m,k]*B[j,k]; two-level z batch (zb=z>>3, zh=z&7); split-K sCh.
// EPI: 3 bf16 +bias[j](nullable) | 4 bf16 +bias[m]
//      6 bf16 transposed store [j,m] +bias[m] | 7 f32 partial
template <int BM, int BN, int EPI, int SPLITK>
__global__ __launch_bounds__(256, 2) void gemm_nt(
    const u16* __restrict__ A, const u16* __restrict__ B, void* __restrict__ Cout,
    const float* __restrict__ bias, int K, int lda, int ldb, int ldc,
    long sA0, long sA1, long sB0, long sB1, long sC0, long sC1, long sCh,
    int nz, float alpha) {
  constexpr int BK = 64;
  constexpr int WM = BM / 2, WN = BN / 2;
  constexpr int FM = WM / 16, FN = WN / 16;
  constexpr int CA = BM / 32, CB = BN / 32;

  __shared__ __attribute__((aligned(16))) u16 As[BM * BK];
  __shared__ __attribute__((aligned(16))) u16 Bs[BN * BK];

  int z, chunk;
  if constexpr (SPLITK > 1) { z = blockIdx.z % nz; chunk = blockIdx.z / nz; }
  else { z = blockIdx.z; chunk = 0; }
  int zb = z >> 3, zh = z & 7;
  A += (long)zb * sA0 + (long)zh * sA1;
  B += (long)zb * sB0 + (long)zh * sB1;
  long coff = (long)zb * sC0 + (long)zh * sC1 + (long)chunk * sCh;

  int tid = threadIdx.x;
  int lane = tid & 63, wid = tid >> 6;
  int wr = wid >> 1, wc = wid & 1;
  int row0 = blockIdx.x * BM, col0 = blockIdx.y * BN;

  int Kc = K / SPLITK;
  int kbeg = chunk * Kc;

  f32x4 acc[FM][FN] = {};

  for (int k0 = kbeg; k0 < kbeg + Kc; k0 += BK) {
#pragma unroll
    for (int i = 0; i < CA; ++i) {
      int c = tid + i * 256;
      GLD(A + (long)(row0 + (c >> 3)) * lda + k0 + (c & 7) * 8, As + c * 8);
    }
#pragma unroll
    for (int i = 0; i < CB; ++i) {
      int c = tid + i * 256;
      GLD(B + (long)(col0 + (c >> 3)) * ldb + k0 + (c & 7) * 8, Bs + c * 8);
    }
    __syncthreads();

    int lr = lane & 15, lk = (lane >> 4) * 8;
#pragma unroll
    for (int kk = 0; kk < BK; kk += 32) {
      short8 af[FM], bfr[FN];
#pragma unroll
      for (int mi = 0; mi < FM; ++mi)
        af[mi] = *reinterpret_cast<const short8*>(&As[(wr * WM + mi * 16 + lr) * BK + kk + lk]);
#pragma unroll
      for (int nj = 0; nj < FN; ++nj)
        bfr[nj] = *reinterpret_cast<const short8*>(&Bs[(wc * WN + nj * 16 + lr) * BK + kk + lk]);
#pragma unroll
      for (int mi = 0; mi < FM; ++mi)
#pragma unroll
        for (int nj = 0; nj < FN; ++nj)
          acc[mi][nj] = MFMA16(af[mi], bfr[nj], acc[mi][nj], 0, 0, 0);
    }
    __syncthreads();
  }

  int lc = lane & 15, rb = (lane >> 4) * 4;
#pragma unroll
  for (int mi = 0; mi < FM; ++mi) {
#pragma unroll
    for (int nj = 0; nj < FN; ++nj) {
      int j = col0 + wc * WN + nj * 16 + lc;
      int m0 = row0 + wr * WM + mi * 16 + rb;
#pragma unroll
      for (int r = 0; r < 4; ++r) {
        int m = m0 + r;
        float v = acc[mi][nj][r];
        if constexpr (EPI == 3) {
          float bi = bias ? bias[j] : 0.f;
          reinterpret_cast<u16*>(Cout)[coff + (long)m * ldc + j] = f2bf(v + bi);
        } else if constexpr (EPI == 4) {
          reinterpret_cast<u16*>(Cout)[coff + (long)m * ldc + j] = f2bf(v + bias[m]);
        } else if constexpr (EPI == 6) {
          reinterpret_cast<u16*>(Cout)[coff + (long)j * ldc + m] = f2bf(v + bias[m]);
        } else {  // 7: f32 split-K partial
          reinterpret_cast<float*>(Cout)[coff + (long)m * ldc + j] = v;
        }
      }
    }
  }
}

// ---------------- split-K reduce: sum 8 f32 chunks -> bf16 ----------------
__global__ __launch_bounds__(256) void reduce8_kernel(const float* __restrict__ part,
                                                      u16* __restrict__ out) {
  int i = blockIdx.x * 256 + threadIdx.x;
  const float4* p = reinterpret_cast<const float4*>(part);
  float4 s = p[i];
#pragma unroll
  for (int c = 1; c < 8; ++c) {
    float4 t = p[i + c * 131072];
    s.x += t.x; s.y += t.y; s.z += t.z; s.w += t.w;
  }
  ushort4 o;
  o.x = f2bf(s.x); o.y = f2bf(s.y); o.z = f2bf(s.z); o.w = f2bf(s.w);
  reinterpret_cast<ushort4*>(out)[i] = o;
}

// ---------------- fused attention: S=Q.Kp^T, softmax, O=P.Vp ----------------
__global__ __launch_bounds__(512, 2) void attn_kernel(
    const u16* __restrict__ Q, const u16* __restrict__ Kp,
    const u16* __restrict__ Vpt, u16* __restrict__ O) {
  constexpr int LQ = 72, LKP = 72, LVP = 264, LP = 264;
  __shared__ __attribute__((aligned(16))) u16 Q_s[128 * LQ];
  __shared__ __attribute__((aligned(16))) u16 Kp_s[256 * LKP];
  __shared__ __attribute__((aligned(16))) u16 Vp_s[64 * LVP];
  __shared__ __attribute__((aligned(16))) u16 P_s[128 * LP];

  int n0 = blockIdx.x * 128;
  int bh = blockIdx.y;
  int b = bh >> 3, h = bh & 7;
  long qbase = ((long)b * N_ + n0) * 512 + h * 64;
  const u16* Kpb = Kp + ((long)b * KD_) * 512 + h * 64;
  const u16* Vpb = Vpt + ((long)b * 512 + h * 64) * KD_;

  int tid = threadIdx.x;
#pragma unroll
  for (int i = 0; i < 2; ++i) {
    int c = tid + i * 512;
    int r = c >> 3, c8 = (c & 7) * 8;
    *reinterpret_cast<uint4*>(&Q_s[r * LQ + c8]) =
        *reinterpret_cast<const uint4*>(Q + qbase + (long)r * 512 + c8);
  }
#pragma unroll
  for (int i = 0; i < 4; ++i) {
    int c = tid + i * 512;
    int r = c >> 3, c8 = (c & 7) * 8;
    *reinterpret_cast<uint4*>(&Kp_s[r * LKP + c8]) =
        *reinterpret_cast<const uint4*>(Kpb + (long)r * 512 + c8);
  }
#pragma unroll
  for (int i = 0; i < 4; ++i) {
    int c = tid + i * 512;
    int r = c >> 5, c8 = (c & 31) * 8;
    *reinterpret_cast<uint4*>(&Vp_s[r * LVP + c8]) =
        *reinterpret_cast<const uint4*>(Vpb + (long)r * KD_ + c8);
  }
  __syncthreads();

  int lane = tid & 63, w = tid >> 6;
  int q0 = w * 16;
  int lr = lane & 15, lk = (lane >> 4) * 8;
  int lc = lane & 15, rb = (lane >> 4) * 4;

  f32x4 acc[16] = {};
  short8 af0 = *reinterpret_cast<const short8*>(&Q_s[(q0 + lr) * LQ + lk]);
  short8 af1 = *reinterpret_cast<const short8*>(&Q_s[(q0 + lr) * LQ + 32 + lk]);
#pragma unroll
  for (int t = 0; t < 16; ++t) {
    short8 b0 = *reinterpret_cast<const short8*>(&Kp_s[(t * 16 + lr) * LKP + lk]);
    short8 b1 = *reinterpret_cast<const short8*>(&Kp_s[(t * 16 + lr) * LKP + 32 + lk]);
    acc[t] = MFMA16(af0, b0, acc[t], 0, 0, 0);
    acc[t] = MFMA16(af1, b1, acc[t], 0, 0, 0);
  }

  float mx[4] = {-3.4e38f, -3.4e38f, -3.4e38f, -3.4e38f};
#pragma unroll
  for (int t = 0; t < 16; ++t)
#pragma unroll
    for (int r = 0; r < 4; ++r) {
      acc[t][r] *= 0.125f;
      mx[r] = fmaxf(mx[r], acc[t][r]);
    }
#pragma unroll
  for (int o = 1; o < 16; o <<= 1)
#pragma unroll
    for (int r = 0; r < 4; ++r) mx[r] = fmaxf(mx[r], __shfl_xor(mx[r], o));
  float sm[4] = {0.f, 0.f, 0.f, 0.f};
#pragma unroll
  for (int t = 0; t < 16; ++t)
#pragma unroll
    for (int r = 0; r < 4; ++r) {
      float e = __expf(acc[t][r] - mx[r]);
      acc[t][r] = e;
      sm[r] += e;
    }
#pragma unroll
  for (int o = 1; o < 16; o <<= 1)
#pragma unroll
    for (int r = 0; r < 4; ++r) sm[r] += __shfl_xor(sm[r], o);
  float inv[4];
#pragma unroll
  for (int r = 0; r < 4; ++r) inv[r] = 1.f / sm[r];
#pragma unroll
  for (int t = 0; t < 16; ++t)
#pragma unroll
    for (int r = 0; r < 4; ++r)
      P_s[(q0 + rb + r) * LP + t * 16 + lc] = f2bf(acc[t][r] * inv[r]);

  f32x4 o2[4] = {};
#pragma unroll
  for (int kk = 0; kk < 8; ++kk) {
    short8 pa = *reinterpret_cast<const short8*>(&P_s[(q0 + lr) * LP + kk * 32 + lk]);
#pragma unroll
    for (int nj = 0; nj < 4; ++nj) {
      short8 vb = *reinterpret_cast<const short8*>(&Vp_s[(nj * 16 + lr) * LVP + kk * 32 + lk]);
      o2[nj] = MFMA16(pa, vb, o2[nj], 0, 0, 0);
    }
  }
#pragma unroll
  for (int nj = 0; nj < 4; ++nj)
#pragma unroll
    for (int r = 0; r < 4; ++r)
      O[qbase + (long)(q0 + rb + r) * 512 + nj * 16 + lc] = f2bf(o2[nj][r]);
}

// ---------------- residual add + LayerNorm (row of 512), bf16 residual stream --------
__global__ __launch_bounds__(256) void add_ln_kernel(
    const float* __restrict__ xin32, const u16* __restrict__ xinb,
    const u16* __restrict__ yin, const float* __restrict__ g,
    const float* __restrict__ bt, float* __restrict__ xout32,
    u16* __restrict__ xbout) {
  int row = blockIdx.x * 4 + (threadIdx.x >> 6);
  int lane = threadIdx.x & 63;
  long base = (long)row * C_ + lane * 8;
  float s[8];
  if (xin32) {
    float4 a0 = *reinterpret_cast<const float4*>(xin32 + base);
    float4 a1 = *reinterpret_cast<const float4*>(xin32 + base + 4);
    s[0] = a0.x; s[1] = a0.y; s[2] = a0.z; s[3] = a0.w;
    s[4] = a1.x; s[5] = a1.y; s[6] = a1.z; s[7] = a1.w;
  } else {
    ushort4 x0 = *reinterpret_cast<const ushort4*>(xinb + base);
    ushort4 x1 = *reinterpret_cast<const ushort4*>(xinb + base + 4);
    s[0] = bf2f(x0.x); s[1] = bf2f(x0.y); s[2] = bf2f(x0.z); s[3] = bf2f(x0.w);
    s[4] = bf2f(x1.x); s[5] = bf2f(x1.y); s[6] = bf2f(x1.z); s[7] = bf2f(x1.w);
  }
  ushort4 u0 = *reinterpret_cast<const ushort4*>(yin + base);
  ushort4 u1 = *reinterpret_cast<const ushort4*>(yin + base + 4);
  s[0] += bf2f(u0.x); s[1] += bf2f(u0.y); s[2] += bf2f(u0.z); s[3] += bf2f(u0.w);
  s[4] += bf2f(u1.x); s[5] += bf2f(u1.y); s[6] += bf2f(u1.z); s[7] += bf2f(u1.w);
  float sum = 0.f;
#pragma unroll
  for (int i = 0; i < 8; ++i) sum += s[i];
#pragma unroll
  for (int o = 1; o < 64; o <<= 1) sum += __shfl_xor(sum, o);
  float mean = sum * (1.f / C_);
  float var = 0.f;
#pragma unroll
  for (int i = 0; i < 8; ++i) { float d = s[i] - mean; var += d * d; }
#pragma unroll
  for (int o = 1; o < 64; o <<= 1) var += __shfl_xor(var, o);
  float inv = rsqrtf(var * (1.f / C_) + 1e-5f);
  int c0 = lane * 8;
  float o[8];
#pragma unroll
  for (int i = 0; i < 8; ++i) o[i] = (s[i] - mean) * inv * g[c0 + i] + bt[c0 + i];
  if (xout32) {
    float4 f0 = {o[0], o[1], o[2], o[3]};
    float4 f1 = {o[4], o[5], o[6], o[7]};
    *reinterpret_cast<float4*>(xout32 + base) = f0;
    *reinterpret_cast<float4*>(xout32 + base + 4) = f1;
  }
  if (xbout) {
    ushort4 w0 = {f2bf(o[0]), f2bf(o[1]), f2bf(o[2]), f2bf(o[3])};
    ushort4 w1 = {f2bf(o[4]), f2bf(o[5]), f2bf(o[6]), f2bf(o[7])};
    *reinterpret_cast<ushort4*>(xbout + base) = w0;
    *reinterpret_cast<ushort4*>(xbout + base + 4) = w1;
  }
}

extern "C" void kernel_launch(void* const* d_in, const int* in_sizes, int n_in,
                              void* d_out, int out_size, void* d_ws, size_t ws_size,
                              hipStream_t stream) {
  const float* x    = (const float*)d_in[0];
  const float* Wq   = (const float*)d_in[1];
  const float* Wk   = (const float*)d_in[2];
  const float* Wv   = (const float*)d_in[3];
  const float* Wo   = (const float*)d_in[4];
  const float* bo   = (const float*)d_in[5];
  const float* ln1g = (const float*)d_in[6];
  const float* ln1b = (const float*)d_in[7];
  const float* W1   = (const float*)d_in[8];
  const float* b1   = (const float*)d_in[9];
  const float* W2   = (const float*)d_in[10];
  const float* b2   = (const float*)d_in[11];
  const float* ln2g = (const float*)d_in[12];
  const float* ln2b = (const float*)d_in[13];
  const float* Ew   = (const float*)d_in[14];
  const float* Eb   = (const float*)d_in[15];
  float* xc = (float*)d_out;  // final f32 output only

  char* wsp = (char*)d_ws;
  size_t off = 0;
  auto alloc = [&](size_t bytes) -> void* {
    void* p = wsp + off;
    off = (off + bytes + 255) & ~(size_t)255;
    return p;
  };
  u16* xb  = (u16*)alloc(8388608UL * 2);   // x bf16 [B,N,C]
  u16* BIG = (u16*)alloc(16777216UL * 2);  // 32MB: xT+xE-partials | h1 chunk
  u16* Qb  = (u16*)alloc(8388608UL * 2);   // Q [B,N,H*D]; attn-out in place
  u16* yb  = (u16*)alloc(8388608UL * 2);   // y bf16 [B,N,C]
  u16* xEb = (u16*)alloc(524288UL * 2);    // xE bf16 [B,KD,C]
  u16* Kpb = (u16*)alloc(524288UL * 2);    // Kp [B,KD,H*D]
  u16* Vpt = (u16*)alloc(524288UL * 2);    // Vp^T [B,H*D,KD]
  u16* wqb = (u16*)alloc(524288UL * 2);
  u16* wkb = (u16*)alloc(524288UL * 2);
  u16* wvb = (u16*)alloc(524288UL * 2);
  u16* wob = (u16*)alloc(524288UL * 2);
  u16* w1b = (u16*)alloc(2097152UL * 2);
  u16* w2b = (u16*)alloc(2097152UL * 2);
  u16* ewb = (u16*)alloc(1048576UL * 2);
  (void)ws_size; (void)in_sizes; (void)n_in; (void)out_size;

  auto cvt = [&](const float* src, u16* dst, long n) {
    int n4 = (int)(n / 4);
    cvt_kernel<<<dim3((n4 + 255) / 256), dim3(256), 0, stream>>>(src, dst, n4);
  };
  cvt(x, xb, 8388608);
  cvt(Wq, wqb, 524288);
  cvt(Wk, wkb, 524288);
  cvt(Wv, wvb, 524288);
  cvt(Wo, wob, 524288);
  cvt(W1, w1b, 2097152);
  cvt(W2, w2b, 2097152);
  cvt(Ew, ewb, 1048576);

  for (int l = 0; l < L_; ++l) {
    const u16* wq = wqb + (long)l * 262144;
    const u16* wk = wkb + (long)l * 262144;
    const u16* wv = wvb + (long)l * 262144;
    const u16* wo = wob + (long)l * 262144;
    const u16* w1 = w1b + (long)l * 1048576;
    const u16* w2 = w2b + (long)l * 1048576;

    // ---- phase A: shared E-projection xE = (Ew . x) once ----
    u16* xT = BIG;
    float* partF = (float*)(BIG + 8388608);
    transpose_kernel<<<dim3(64, 8, 4), dim3(256), 0, stream>>>(xb, xT);
    gemm_nt<128, 128, 7, 8><<<dim3(2, 4, 32), dim3(256), 0, stream>>>(
        ewb, xT, partF, nullptr, 4096, 4096, 4096, 512,
        0, 0, 0, 2097152, 0, 131072, 524288, 4, 1.f);
    reduce8_kernel<<<dim3(512), dim3(256), 0, stream>>>(partF, xEb);
    gemm_nt<128, 128, 4, 1><<<dim3(2, 4, 4), dim3(256), 0, stream>>>(
        xEb, wk, Kpb, Eb, 512, 512, 512, 512,
        0, 131072, 0, 0, 0, 131072, 0, 4, 1.f);
    gemm_nt<128, 128, 6, 1><<<dim3(2, 4, 4), dim3(256), 0, stream>>>(
        xEb, wv, Vpt, Eb, 512, 512, 512, 256,
        0, 131072, 0, 0, 0, 131072, 0, 4, 1.f);
    // Q = x @ Wq^T -> [B,N,H*D]  (256^2 8-phase)
    gemm256_nt<0><<<dim3(64, 2), dim3(512), 0, stream>>>(
        xb, wq, Qb, nullptr, 512, 512, 512, 512);

    // ---- phase B: fused attention ----
    attn_kernel<<<dim3(32, 32), dim3(512), 0, stream>>>(Qb, Kpb, Vpt, Qb);

    // y = o @ Wo^T + bo  (256^2 8-phase)
    gemm256_nt<1><<<dim3(64, 2), dim3(512), 0, stream>>>(
        Qb, wo, yb, bo + (long)l * 512, 512, 512, 512, 512);
    add_ln_kernel<<<dim3(4096), dim3(256), 0, stream>>>(
        l == 0 ? x : nullptr, l == 0 ? nullptr : xb, yb,
        ln1g + (long)l * 512, ln1b + (long)l * 512, nullptr, xb);

    // ---- phase C: FFN in 2 chunks of 8192 rows ----
    for (int ch = 0; ch < 2; ++ch) {
      u16* h1 = BIG;
      const u16* xch = xb + (long)ch * 4194304;
      gemm256_nt<2><<<dim3(32, 8), dim3(512), 0, stream>>>(
          xch, w1, h1, b1 + (long)l * 2048, 512, 512, 512, 2048);
      gemm_nt<128, 64, 3, 1><<<dim3(64, 8, 1), dim3(256), 0, stream>>>(
          h1, w2, yb + (long)ch * 4194304, b2 + (long)l * 512,
          2048, 2048, 2048, 512, 0, 0, 0, 0, 0, 0, 0, 1, 1.f);
    }
    add_ln_kernel<<<dim3(4096), dim3(256), 0, stream>>>(
        nullptr, xb, yb, ln2g + (long)l * 512, ln2b + (long)l * 512,
        (l == L_ - 1) ? xc : nullptr, (l == L_ - 1) ? (u16*)nullptr : xb);
  }
}

// Round 7
// 588.190 us; speedup vs baseline: 2.6211x; 1.0651x over previous
//
#include <hip/hip_runtime.h>
#include <math.h>

typedef unsigned short u16;
typedef __attribute__((ext_vector_type(8))) short short8;
typedef __attribute__((ext_vector_type(4))) float f32x4;

#define B_ 4
#define N_ 4096
#define C_ 512
#define H_ 8
#define D_ 64
#define KD_ 256
#define FF_ 2048
#define L_ 2

__device__ __forceinline__ float bf2f(u16 x) {
  return __builtin_bit_cast(float, (unsigned int)x << 16);
}
__device__ __forceinline__ u16 f2bf(float f) {
  unsigned int t = __builtin_bit_cast(unsigned int, f);
  return (u16)((t + 0x7fffu + ((t >> 16) & 1u)) >> 16);
}

// async global->LDS, 16B per lane
#define GLD(g, l)                                                             \
  __builtin_amdgcn_global_load_lds(                                           \
      (const __attribute__((address_space(1))) void*)(g),                     \
      (__attribute__((address_space(3))) void*)(l), 16, 0, 0)

#define MFMA16 __builtin_amdgcn_mfma_f32_16x16x32_bf16

// ---------------- f32 -> bf16 convert ----------------
__global__ __launch_bounds__(256) void cvt_kernel(const float* __restrict__ in,
                                                  u16* __restrict__ out, int n4) {
  int i = blockIdx.x * 256 + threadIdx.x;
  if (i >= n4) return;
  float4 v = reinterpret_cast<const float4*>(in)[i];
  ushort4 o;
  o.x = f2bf(v.x); o.y = f2bf(v.y); o.z = f2bf(v.z); o.w = f2bf(v.w);
  reinterpret_cast<ushort4*>(out)[i] = o;
}

// ---------------- bf16 transpose [B,N,C] -> [B,C,N], 64x64 tiles ----------------
__global__ __launch_bounds__(256) void transpose_kernel(const u16* __restrict__ in,
                                                        u16* __restrict__ out) {
  __shared__ u16 T[64][72];
  int n0 = blockIdx.x * 64, c0 = blockIdx.y * 64, b = blockIdx.z;
  const u16* src = in + (long)b * N_ * C_;
  u16* dst = out + (long)b * C_ * N_;
  int t = threadIdx.x;
  int r = t >> 3, cq = (t & 7) * 8;
#pragma unroll
  for (int h = 0; h < 2; ++h) {
    const u16* p = src + (long)(n0 + r + h * 32) * C_ + c0 + cq;
    ushort4 v0 = *reinterpret_cast<const ushort4*>(p);
    ushort4 v1 = *reinterpret_cast<const ushort4*>(p + 4);
    T[r + h * 32][cq + 0] = v0.x; T[r + h * 32][cq + 1] = v0.y;
    T[r + h * 32][cq + 2] = v0.z; T[r + h * 32][cq + 3] = v0.w;
    T[r + h * 32][cq + 4] = v1.x; T[r + h * 32][cq + 5] = v1.y;
    T[r + h * 32][cq + 6] = v1.z; T[r + h * 32][cq + 7] = v1.w;
  }
  __syncthreads();
  int cc = t >> 3, nq = (t & 7) * 8;
#pragma unroll
  for (int h = 0; h < 2; ++h) {
    int cl = cc + h * 32;
    ushort4 w0, w1;
    w0.x = T[nq + 0][cl]; w0.y = T[nq + 1][cl];
    w0.z = T[nq + 2][cl]; w0.w = T[nq + 3][cl];
    w1.x = T[nq + 4][cl]; w1.y = T[nq + 5][cl];
    w1.z = T[nq + 6][cl]; w1.w = T[nq + 7][cl];
    u16* q = dst + (long)(c0 + cl) * N_ + n0 + nq;
    *reinterpret_cast<ushort4*>(q) = w0;
    *reinterpret_cast<ushort4*>(q + 4) = w1;
  }
}

// ---------------- 8-phase-style counted-vmcnt MFMA GEMM (NT) ----------------
// C[m,j] = sum_k A[m,k]*B[j,k]. BM=256, BK=32, 4 LDS buffers (2-tile prefetch),
// counted vmcnt (never 0 in loop), XOR swizzle (2-way banks), setprio, XCD swizzle.
// 512 thr = 8 waves arranged (256/WM) x (BN/WN).
// EPI: 0 bf16 | 1 bf16 +bias[j] | 2 bf16 gelu(v+bias[j]) | 8 f32 out32 | 9 bf16 v+acc32+bias[j]
template <int BN, int WM, int WN, int EPI>
__global__ __launch_bounds__(512, 2) void gemm8p(
    const u16* __restrict__ A, const u16* __restrict__ B, u16* __restrict__ C,
    const float* __restrict__ bias, const float* __restrict__ acc32,
    float* __restrict__ out32, int K, int lda, int ldb, int ldc) {
  constexpr int BM = 256, BK = 32;
  constexpr int GB = (BN * BK) / (512 * 8);  // B GLDs/thread/tile: 2 (BN=256) or 1 (BN=128)
  constexpr int G = 2 + GB;
  constexpr int FM = WM / 16, FN = WN / 16;
  constexpr int NWN = BN / WN;
  constexpr int FM0 = FM / 2;

  __shared__ __attribute__((aligned(16))) u16 As[4][BM * BK];
  __shared__ __attribute__((aligned(16))) u16 Bs[4][BN * BK];

  // XCD-chunked bijective swizzle (all grids have nwg % 8 == 0)
  int gy = gridDim.y;
  int nwg = gridDim.x * gy;
  int id = blockIdx.x * gy + blockIdx.y;
  int nid = (id & 7) * (nwg >> 3) + (id >> 3);
  int row0 = (nid / gy) * BM, col0 = (nid % gy) * BN;

  int tid = threadIdx.x;
  int lane = tid & 63, wid = tid >> 6;
  int wr = wid / NWN, wc = wid % NWN;
  int lr = lane & 15, q = lane >> 4;

  // stage: LDS chunk c=(row<<2)|ck holds global k-chunk (ck ^ ((row>>1)&3))
  auto stA = [&](int buf, int k0) {
#pragma unroll
    for (int g = 0; g < 2; ++g) {
      int c = g * 512 + tid;
      int r = c >> 2, ck = c & 3;
      GLD(A + (long)(row0 + r) * lda + k0 + ((ck ^ ((r >> 1) & 3)) << 3),
          &As[buf][c * 8]);
    }
  };
  auto stB = [&](int buf, int k0) {
#pragma unroll
    for (int g = 0; g < GB; ++g) {
      int c = g * 512 + tid;
      int r = c >> 2, ck = c & 3;
      GLD(B + (long)(col0 + r) * ldb + k0 + ((ck ^ ((r >> 1) & 3)) << 3),
          &Bs[buf][c * 8]);
    }
  };
  // swizzled read of logical chunk q of row r
  auto rd = [&](const u16* Tb, int r) {
    return *reinterpret_cast<const short8*>(&Tb[r * 32 + ((q ^ ((r >> 1) & 3)) << 3)]);
  };

  f32x4 acc[FM][FN] = {};
  int NT = K / BK;

  // prologue: 3 tiles in flight (3G loads)
  stA(0, 0); stB(0, 0);
  stA(1, BK); stB(1, BK);
  stA(2, 2 * BK); stB(2, 2 * BK);

  for (int t = 0; t < NT; ++t) {
    const u16* Ab = As[t & 3];
    const u16* Bb = Bs[t & 3];
    bool pf = (t + 3) < NT;
    int bn = (t + 3) & 3, kn = (t + 3) * BK;

    // counted wait: tile t landed, tiles t+1,t+2 (2G loads) stay in flight
    if constexpr (G == 4) asm volatile("s_waitcnt vmcnt(8)" ::: "memory");
    else                  asm volatile("s_waitcnt vmcnt(6)" ::: "memory");
    __builtin_amdgcn_s_barrier();

    short8 bf[FN], af[FM0];
    // ---- phase 0: B frags + A rows 0..FM0-1, issue next A stage ----
#pragma unroll
    for (int nj = 0; nj < FN; ++nj) bf[nj] = rd(Bb, wc * WN + nj * 16 + lr);
#pragma unroll
    for (int mi = 0; mi < FM0; ++mi) af[mi] = rd(Ab, wr * WM + mi * 16 + lr);
    if (pf) stA(bn, kn);
    __builtin_amdgcn_s_barrier();
    asm volatile("s_waitcnt lgkmcnt(0)" ::: "memory");
    __builtin_amdgcn_sched_barrier(0);
    __builtin_amdgcn_s_setprio(1);
#pragma unroll
    for (int mi = 0; mi < FM0; ++mi)
#pragma unroll
      for (int nj = 0; nj < FN; ++nj)
        acc[mi][nj] = MFMA16(af[mi], bf[nj], acc[mi][nj], 0, 0, 0);
    __builtin_amdgcn_s_setprio(0);
    __builtin_amdgcn_s_barrier();
    // ---- phase 1: A rows FM0..FM-1, issue next B stage ----
#pragma unroll
    for (int mi = 0; mi < FM - FM0; ++mi)
      af[mi] = rd(Ab, wr * WM + (FM0 + mi) * 16 + lr);
    if (pf) stB(bn, kn);
    __builtin_amdgcn_s_barrier();
    asm volatile("s_waitcnt lgkmcnt(0)" ::: "memory");
    __builtin_amdgcn_sched_barrier(0);
    __builtin_amdgcn_s_setprio(1);
#pragma unroll
    for (int mi = 0; mi < FM - FM0; ++mi)
#pragma unroll
      for (int nj = 0; nj < FN; ++nj)
        acc[FM0 + mi][nj] = MFMA16(af[mi], bf[nj], acc[FM0 + mi][nj], 0, 0, 0);
    __builtin_amdgcn_s_setprio(0);
    __builtin_amdgcn_s_barrier();
  }

  // epilogue: C/D layout col=lane&15, row=(lane>>4)*4+reg
  int lc = lane & 15, rb = (lane >> 4) * 4;
#pragma unroll
  for (int mi = 0; mi < FM; ++mi) {
#pragma unroll
    for (int nj = 0; nj < FN; ++nj) {
      int j = col0 + wc * WN + nj * 16 + lc;
      int m0 = row0 + wr * WM + mi * 16 + rb;
#pragma unroll
      for (int r = 0; r < 4; ++r) {
        long m = m0 + r;
        float v = acc[mi][nj][r];
        if constexpr (EPI == 0) {
          C[m * ldc + j] = f2bf(v);
        } else if constexpr (EPI == 1) {
          C[m * ldc + j] = f2bf(v + bias[j]);
        } else if constexpr (EPI == 2) {  // fast tanh-GELU
          float tt = v + bias[j];
          float u = tt * (0.7978845608f + 0.0356774081f * tt * tt);
          float e = __expf(2.f * u);
          float th = 1.f - 2.f / (e + 1.f);
          C[m * ldc + j] = f2bf(0.5f * tt * (1.f + th));
        } else if constexpr (EPI == 8) {  // f32 partial
          out32[m * ldc + j] = v;
        } else {  // 9: add f32 partial + bias -> bf16
          C[m * ldc + j] = f2bf(v + acc32[m * ldc + j] + bias[j]);
        }
      }
    }
  }
}

// ---------------- generic 128-tile NT MFMA GEMM (xE/Kp/Vp only) ----------------
// EPI: 4 bf16 +bias[m] | 6 bf16 transposed store [j,m] +bias[m] | 7 f32 partial
template <int BM, int BN, int EPI, int SPLITK>
__global__ __launch_bounds__(256, 2) void gemm_nt(
    const u16* __restrict__ A, const u16* __restrict__ B, void* __restrict__ Cout,
    const float* __restrict__ bias, int K, int lda, int ldb, int ldc,
    long sA0, long sA1, long sB0, long sB1, long sC0, long sC1, long sCh,
    int nz, float alpha) {
  constexpr int BK = 64;
  constexpr int WM = BM / 2, WN = BN / 2;
  constexpr int FM = WM / 16, FN = WN / 16;
  constexpr int CA = BM / 32, CB = BN / 32;

  __shared__ __attribute__((aligned(16))) u16 As[BM * BK];
  __shared__ __attribute__((aligned(16))) u16 Bs[BN * BK];

  int z, chunk;
  if constexpr (SPLITK > 1) { z = blockIdx.z % nz; chunk = blockIdx.z / nz; }
  else { z = blockIdx.z; chunk = 0; }
  int zb = z >> 3, zh = z & 7;
  A += (long)zb * sA0 + (long)zh * sA1;
  B += (long)zb * sB0 + (long)zh * sB1;
  long coff = (long)zb * sC0 + (long)zh * sC1 + (long)chunk * sCh;

  int tid = threadIdx.x;
  int lane = tid & 63, wid = tid >> 6;
  int wr = wid >> 1, wc = wid & 1;
  int row0 = blockIdx.x * BM, col0 = blockIdx.y * BN;

  int Kc = K / SPLITK;
  int kbeg = chunk * Kc;

  f32x4 acc[FM][FN] = {};

  for (int k0 = kbeg; k0 < kbeg + Kc; k0 += BK) {
#pragma unroll
    for (int i = 0; i < CA; ++i) {
      int c = tid + i * 256;
      GLD(A + (long)(row0 + (c >> 3)) * lda + k0 + (c & 7) * 8, As + c * 8);
    }
#pragma unroll
    for (int i = 0; i < CB; ++i) {
      int c = tid + i * 256;
      GLD(B + (long)(col0 + (c >> 3)) * ldb + k0 + (c & 7) * 8, Bs + c * 8);
    }
    __syncthreads();

    int lr = lane & 15, lk = (lane >> 4) * 8;
#pragma unroll
    for (int kk = 0; kk < BK; kk += 32) {
      short8 af[FM], bfr[FN];
#pragma unroll
      for (int mi = 0; mi < FM; ++mi)
        af[mi] = *reinterpret_cast<const short8*>(&As[(wr * WM + mi * 16 + lr) * BK + kk + lk]);
#pragma unroll
      for (int nj = 0; nj < FN; ++nj)
        bfr[nj] = *reinterpret_cast<const short8*>(&Bs[(wc * WN + nj * 16 + lr) * BK + kk + lk]);
#pragma unroll
      for (int mi = 0; mi < FM; ++mi)
#pragma unroll
        for (int nj = 0; nj < FN; ++nj)
          acc[mi][nj] = MFMA16(af[mi], bfr[nj], acc[mi][nj], 0, 0, 0);
    }
    __syncthreads();
  }

  int lc = lane & 15, rb = (lane >> 4) * 4;
#pragma unroll
  for (int mi = 0; mi < FM; ++mi) {
#pragma unroll
    for (int nj = 0; nj < FN; ++nj) {
      int j = col0 + wc * WN + nj * 16 + lc;
      int m0 = row0 + wr * WM + mi * 16 + rb;
#pragma unroll
      for (int r = 0; r < 4; ++r) {
        int m = m0 + r;
        float v = acc[mi][nj][r];
        if constexpr (EPI == 4) {
          reinterpret_cast<u16*>(Cout)[coff + (long)m * ldc + j] = f2bf(v + bias[m]);
        } else if constexpr (EPI == 6) {
          reinterpret_cast<u16*>(Cout)[coff + (long)j * ldc + m] = f2bf(v + bias[m]);
        } else {  // 7: f32 split-K partial
          reinterpret_cast<float*>(Cout)[coff + (long)m * ldc + j] = v;
        }
      }
    }
  }
}

// ---------------- split-K reduce: sum 8 f32 chunks -> bf16 ----------------
__global__ __launch_bounds__(256) void reduce8_kernel(const float* __restrict__ part,
                                                      u16* __restrict__ out) {
  int i = blockIdx.x * 256 + threadIdx.x;
  const float4* p = reinterpret_cast<const float4*>(part);
  float4 s = p[i];
#pragma unroll
  for (int c = 1; c < 8; ++c) {
    float4 t = p[i + c * 131072];
    s.x += t.x; s.y += t.y; s.z += t.z; s.w += t.w;
  }
  ushort4 o;
  o.x = f2bf(s.x); o.y = f2bf(s.y); o.z = f2bf(s.z); o.w = f2bf(s.w);
  reinterpret_cast<ushort4*>(out)[i] = o;
}

// ---------------- fused attention: S=Q.Kp^T, softmax, O=P.Vp ----------------
__global__ __launch_bounds__(512, 2) void attn_kernel(
    const u16* __restrict__ Q, const u16* __restrict__ Kp,
    const u16* __restrict__ Vpt, u16* __restrict__ O) {
  constexpr int LQ = 72, LKP = 72, LVP = 264, LP = 264;
  __shared__ __attribute__((aligned(16))) u16 Q_s[128 * LQ];
  __shared__ __attribute__((aligned(16))) u16 Kp_s[256 * LKP];
  __shared__ __attribute__((aligned(16))) u16 Vp_s[64 * LVP];
  __shared__ __attribute__((aligned(16))) u16 P_s[128 * LP];

  int n0 = blockIdx.x * 128;
  int bh = blockIdx.y;
  int b = bh >> 3, h = bh & 7;
  long qbase = ((long)b * N_ + n0) * 512 + h * 64;
  const u16* Kpb = Kp + ((long)b * KD_) * 512 + h * 64;
  const u16* Vpb = Vpt + ((long)b * 512 + h * 64) * KD_;

  int tid = threadIdx.x;
#pragma unroll
  for (int i = 0; i < 2; ++i) {
    int c = tid + i * 512;
    int r = c >> 3, c8 = (c & 7) * 8;
    *reinterpret_cast<uint4*>(&Q_s[r * LQ + c8]) =
        *reinterpret_cast<const uint4*>(Q + qbase + (long)r * 512 + c8);
  }
#pragma unroll
  for (int i = 0; i < 4; ++i) {
    int c = tid + i * 512;
    int r = c >> 3, c8 = (c & 7) * 8;
    *reinterpret_cast<uint4*>(&Kp_s[r * LKP + c8]) =
        *reinterpret_cast<const uint4*>(Kpb + (long)r * 512 + c8);
  }
#pragma unroll
  for (int i = 0; i < 4; ++i) {
    int c = tid + i * 512;
    int r = c >> 5, c8 = (c & 31) * 8;
    *reinterpret_cast<uint4*>(&Vp_s[r * LVP + c8]) =
        *reinterpret_cast<const uint4*>(Vpb + (long)r * KD_ + c8);
  }
  __syncthreads();

  int lane = tid & 63, w = tid >> 6;
  int q0 = w * 16;
  int lr = lane & 15, lk = (lane >> 4) * 8;
  int lc = lane & 15, rb = (lane >> 4) * 4;

  f32x4 acc[16] = {};
  short8 af0 = *reinterpret_cast<const short8*>(&Q_s[(q0 + lr) * LQ + lk]);
  short8 af1 = *reinterpret_cast<const short8*>(&Q_s[(q0 + lr) * LQ + 32 + lk]);
#pragma unroll
  for (int t = 0; t < 16; ++t) {
    short8 b0 = *reinterpret_cast<const short8*>(&Kp_s[(t * 16 + lr) * LKP + lk]);
    short8 b1 = *reinterpret_cast<const short8*>(&Kp_s[(t * 16 + lr) * LKP + 32 + lk]);
    acc[t] = MFMA16(af0, b0, acc[t], 0, 0, 0);
    acc[t] = MFMA16(af1, b1, acc[t], 0, 0, 0);
  }

  float mx[4] = {-3.4e38f, -3.4e38f, -3.4e38f, -3.4e38f};
#pragma unroll
  for (int t = 0; t < 16; ++t)
#pragma unroll
    for (int r = 0; r < 4; ++r) {
      acc[t][r] *= 0.125f;
      mx[r] = fmaxf(mx[r], acc[t][r]);
    }
#pragma unroll
  for (int o = 1; o < 16; o <<= 1)
#pragma unroll
    for (int r = 0; r < 4; ++r) mx[r] = fmaxf(mx[r], __shfl_xor(mx[r], o));
  float sm[4] = {0.f, 0.f, 0.f, 0.f};
#pragma unroll
  for (int t = 0; t < 16; ++t)
#pragma unroll
    for (int r = 0; r < 4; ++r) {
      float e = __expf(acc[t][r] - mx[r]);
      acc[t][r] = e;
      sm[r] += e;
    }
#pragma unroll
  for (int o = 1; o < 16; o <<= 1)
#pragma unroll
    for (int r = 0; r < 4; ++r) sm[r] += __shfl_xor(sm[r], o);
  float inv[4];
#pragma unroll
  for (int r = 0; r < 4; ++r) inv[r] = 1.f / sm[r];
#pragma unroll
  for (int t = 0; t < 16; ++t)
#pragma unroll
    for (int r = 0; r < 4; ++r)
      P_s[(q0 + rb + r) * LP + t * 16 + lc] = f2bf(acc[t][r] * inv[r]);

  f32x4 o2[4] = {};
#pragma unroll
  for (int kk = 0; kk < 8; ++kk) {
    short8 pa = *reinterpret_cast<const short8*>(&P_s[(q0 + lr) * LP + kk * 32 + lk]);
#pragma unroll
    for (int nj = 0; nj < 4; ++nj) {
      short8 vb = *reinterpret_cast<const short8*>(&Vp_s[(nj * 16 + lr) * LVP + kk * 32 + lk]);
      o2[nj] = MFMA16(pa, vb, o2[nj], 0, 0, 0);
    }
  }
#pragma unroll
  for (int nj = 0; nj < 4; ++nj)
#pragma unroll
    for (int r = 0; r < 4; ++r)
      O[qbase + (long)(q0 + rb + r) * 512 + nj * 16 + lc] = f2bf(o2[nj][r]);
}

// ---------------- residual add + LayerNorm (row of 512), bf16 residual stream --------
__global__ __launch_bounds__(256) void add_ln_kernel(
    const float* __restrict__ xin32, const u16* __restrict__ xinb,
    const u16* __restrict__ yin, const float* __restrict__ g,
    const float* __restrict__ bt, float* __restrict__ xout32,
    u16* __restrict__ xbout) {
  int row = blockIdx.x * 4 + (threadIdx.x >> 6);
  int lane = threadIdx.x & 63;
  long base = (long)row * C_ + lane * 8;
  float s[8];
  if (xin32) {
    float4 a0 = *reinterpret_cast<const float4*>(xin32 + base);
    float4 a1 = *reinterpret_cast<const float4*>(xin32 + base + 4);
    s[0] = a0.x; s[1] = a0.y; s[2] = a0.z; s[3] = a0.w;
    s[4] = a1.x; s[5] = a1.y; s[6] = a1.z; s[7] = a1.w;
  } else {
    ushort4 x0 = *reinterpret_cast<const ushort4*>(xinb + base);
    ushort4 x1 = *reinterpret_cast<const ushort4*>(xinb + base + 4);
    s[0] = bf2f(x0.x); s[1] = bf2f(x0.y); s[2] = bf2f(x0.z); s[3] = bf2f(x0.w);
    s[4] = bf2f(x1.x); s[5] = bf2f(x1.y); s[6] = bf2f(x1.z); s[7] = bf2f(x1.w);
  }
  ushort4 u0 = *reinterpret_cast<const ushort4*>(yin + base);
  ushort4 u1 = *reinterpret_cast<const ushort4*>(yin + base + 4);
  s[0] += bf2f(u0.x); s[1] += bf2f(u0.y); s[2] += bf2f(u0.z); s[3] += bf2f(u0.w);
  s[4] += bf2f(u1.x); s[5] += bf2f(u1.y); s[6] += bf2f(u1.z); s[7] += bf2f(u1.w);
  float sum = 0.f;
#pragma unroll
  for (int i = 0; i < 8; ++i) sum += s[i];
#pragma unroll
  for (int o = 1; o < 64; o <<= 1) sum += __shfl_xor(sum, o);
  float mean = sum * (1.f / C_);
  float var = 0.f;
#pragma unroll
  for (int i = 0; i < 8; ++i) { float d = s[i] - mean; var += d * d; }
#pragma unroll
  for (int o = 1; o < 64; o <<= 1) var += __shfl_xor(var, o);
  float inv = rsqrtf(var * (1.f / C_) + 1e-5f);
  int c0 = lane * 8;
  float o[8];
#pragma unroll
  for (int i = 0; i < 8; ++i) o[i] = (s[i] - mean) * inv * g[c0 + i] + bt[c0 + i];
  if (xout32) {
    float4 f0 = {o[0], o[1], o[2], o[3]};
    float4 f1 = {o[4], o[5], o[6], o[7]};
    *reinterpret_cast<float4*>(xout32 + base) = f0;
    *reinterpret_cast<float4*>(xout32 + base + 4) = f1;
  }
  if (xbout) {
    ushort4 w0 = {f2bf(o[0]), f2bf(o[1]), f2bf(o[2]), f2bf(o[3])};
    ushort4 w1 = {f2bf(o[4]), f2bf(o[5]), f2bf(o[6]), f2bf(o[7])};
    *reinterpret_cast<ushort4*>(xbout + base) = w0;
    *reinterpret_cast<ushort4*>(xbout + base + 4) = w1;
  }
}

extern "C" void kernel_launch(void* const* d_in, const int* in_sizes, int n_in,
                              void* d_out, int out_size, void* d_ws, size_t ws_size,
                              hipStream_t stream) {
  const float* x    = (const float*)d_in[0];
  const float* Wq   = (const float*)d_in[1];
  const float* Wk   = (const float*)d_in[2];
  const float* Wv   = (const float*)d_in[3];
  const float* Wo   = (const float*)d_in[4];
  const float* bo   = (const float*)d_in[5];
  const float* ln1g = (const float*)d_in[6];
  const float* ln1b = (const float*)d_in[7];
  const float* W1   = (const float*)d_in[8];
  const float* b1   = (const float*)d_in[9];
  const float* W2   = (const float*)d_in[10];
  const float* b2   = (const float*)d_in[11];
  const float* ln2g = (const float*)d_in[12];
  const float* ln2b = (const float*)d_in[13];
  const float* Ew   = (const float*)d_in[14];
  const float* Eb   = (const float*)d_in[15];
  float* xc = (float*)d_out;  // W2 f32 partial scratch + final f32 output

  char* wsp = (char*)d_ws;
  size_t off = 0;
  auto alloc = [&](size_t bytes) -> void* {
    void* p = wsp + off;
    off = (off + bytes + 255) & ~(size_t)255;
    return p;
  };
  u16* xb  = (u16*)alloc(8388608UL * 2);   // x bf16 [B,N,C]
  u16* BIG = (u16*)alloc(16777216UL * 2);  // 32MB: xT+xE-partials | h1 col-chunk [16384,1024]
  u16* Qb  = (u16*)alloc(8388608UL * 2);   // Q [B,N,H*D]; attn-out in place
  u16* yb  = (u16*)alloc(8388608UL * 2);   // y bf16 [B,N,C]
  u16* xEb = (u16*)alloc(524288UL * 2);    // xE bf16 [B,KD,C]
  u16* Kpb = (u16*)alloc(524288UL * 2);    // Kp [B,KD,H*D]
  u16* Vpt = (u16*)alloc(524288UL * 2);    // Vp^T [B,H*D,KD]
  u16* wqb = (u16*)alloc(524288UL * 2);
  u16* wkb = (u16*)alloc(524288UL * 2);
  u16* wvb = (u16*)alloc(524288UL * 2);
  u16* wob = (u16*)alloc(524288UL * 2);
  u16* w1b = (u16*)alloc(2097152UL * 2);
  u16* w2b = (u16*)alloc(2097152UL * 2);
  u16* ewb = (u16*)alloc(1048576UL * 2);
  (void)ws_size; (void)in_sizes; (void)n_in; (void)out_size;

  auto cvt = [&](const float* src, u16* dst, long n) {
    int n4 = (int)(n / 4);
    cvt_kernel<<<dim3((n4 + 255) / 256), dim3(256), 0, stream>>>(src, dst, n4);
  };
  cvt(x, xb, 8388608);
  cvt(Wq, wqb, 524288);
  cvt(Wk, wkb, 524288);
  cvt(Wv, wvb, 524288);
  cvt(Wo, wob, 524288);
  cvt(W1, w1b, 2097152);
  cvt(W2, w2b, 2097152);
  cvt(Ew, ewb, 1048576);

  for (int l = 0; l < L_; ++l) {
    const u16* wq = wqb + (long)l * 262144;
    const u16* wk = wkb + (long)l * 262144;
    const u16* wv = wvb + (long)l * 262144;
    const u16* wo = wob + (long)l * 262144;
    const u16* w1 = w1b + (long)l * 1048576;
    const u16* w2 = w2b + (long)l * 1048576;

    // ---- phase A: shared E-projection xE = (Ew . x) once ----
    u16* xT = BIG;
    float* partF = (float*)(BIG + 8388608);
    transpose_kernel<<<dim3(64, 8, 4), dim3(256), 0, stream>>>(xb, xT);
    gemm_nt<128, 128, 7, 8><<<dim3(2, 4, 32), dim3(256), 0, stream>>>(
        ewb, xT, partF, nullptr, 4096, 4096, 4096, 512,
        0, 0, 0, 2097152, 0, 131072, 524288, 4, 1.f);
    reduce8_kernel<<<dim3(512), dim3(256), 0, stream>>>(partF, xEb);
    gemm_nt<128, 128, 4, 1><<<dim3(2, 4, 4), dim3(256), 0, stream>>>(
        xEb, wk, Kpb, Eb, 512, 512, 512, 512,
        0, 131072, 0, 0, 0, 131072, 0, 4, 1.f);
    gemm_nt<128, 128, 6, 1><<<dim3(2, 4, 4), dim3(256), 0, stream>>>(
        xEb, wv, Vpt, Eb, 512, 512, 512, 256,
        0, 131072, 0, 0, 0, 131072, 0, 4, 1.f);
    // Q = x @ Wq^T  (counted-vmcnt 8p, 256x128 tiles, grid 256)
    gemm8p<128, 64, 64, 0><<<dim3(64, 4), dim3(512), 0, stream>>>(
        xb, wq, Qb, nullptr, nullptr, nullptr, 512, 512, 512, 512);

    // ---- phase B: fused attention ----
    attn_kernel<<<dim3(32, 32), dim3(512), 0, stream>>>(Qb, Kpb, Vpt, Qb);

    // y = o @ Wo^T + bo
    gemm8p<128, 64, 64, 1><<<dim3(64, 4), dim3(512), 0, stream>>>(
        Qb, wo, yb, bo + (long)l * 512, nullptr, nullptr, 512, 512, 512, 512);
    add_ln_kernel<<<dim3(4096), dim3(256), 0, stream>>>(
        l == 0 ? x : nullptr, l == 0 ? nullptr : xb, yb,
        ln1g + (long)l * 512, ln1b + (long)l * 512, nullptr, xb);

    // ---- phase C: FFN column-chunked over FF (full M = 16384 every GEMM) ----
    for (int ch = 0; ch < 2; ++ch) {
      u16* h1 = BIG;  // [16384, 1024]
      // h1 = gelu(x @ W1_slice^T + b1_slice)
      gemm8p<256, 128, 64, 2><<<dim3(64, 4), dim3(512), 0, stream>>>(
          xb, w1 + (long)ch * 1024 * 512, h1, b1 + (long)l * 2048 + ch * 1024,
          nullptr, nullptr, 512, 512, 512, 1024);
      if (ch == 0) {  // f32 partial into d_out scratch
        gemm8p<128, 64, 64, 8><<<dim3(64, 4), dim3(512), 0, stream>>>(
            h1, w2 + 0, nullptr, nullptr, nullptr, xc, 1024, 1024, 2048, 512);
      } else {  // add partial + bias -> bf16 y
        gemm8p<128, 64, 64, 9><<<dim3(64, 4), dim3(512), 0, stream>>>(
            h1, w2 + 1024, yb, b2 + (long)l * 512, xc, nullptr, 1024, 1024, 2048, 512);
      }
    }
    add_ln_kernel<<<dim3(4096), dim3(256), 0, stream>>>(
        nullptr, xb, yb, ln2g + (long)l * 512, ln2b + (long)l * 512,
        (l == L_ - 1) ? xc : nullptr, (l == L_ - 1) ? (u16*)nullptr : xb);
  }
}

// Round 8
// 586.145 us; speedup vs baseline: 2.6302x; 1.0035x over previous
//
#include <hip/hip_runtime.h>
#include <math.h>

typedef unsigned short u16;
typedef __attribute__((ext_vector_type(8))) short short8;
typedef __attribute__((ext_vector_type(4))) float f32x4;

#define B_ 4
#define N_ 4096
#define C_ 512
#define H_ 8
#define D_ 64
#define KD_ 256
#define FF_ 2048
#define L_ 2

__device__ __forceinline__ float bf2f(u16 x) {
  return __builtin_bit_cast(float, (unsigned int)x << 16);
}
__device__ __forceinline__ u16 f2bf(float f) {
  unsigned int t = __builtin_bit_cast(unsigned int, f);
  return (u16)((t + 0x7fffu + ((t >> 16) & 1u)) >> 16);
}

#define GLD(g, l)                                                             \
  __builtin_amdgcn_global_load_lds(                                           \
      (const __attribute__((address_space(1))) void*)(g),                     \
      (__attribute__((address_space(3))) void*)(l), 16, 0, 0)

#define MFMA16 __builtin_amdgcn_mfma_f32_16x16x32_bf16

// ---------------- f32 -> bf16 convert (single tensor) ----------------
__global__ __launch_bounds__(256) void cvt_kernel(const float* __restrict__ in,
                                                  u16* __restrict__ out, int n4) {
  int i = blockIdx.x * 256 + threadIdx.x;
  if (i >= n4) return;
  float4 v = reinterpret_cast<const float4*>(in)[i];
  ushort4 o;
  o.x = f2bf(v.x); o.y = f2bf(v.y); o.z = f2bf(v.z); o.w = f2bf(v.w);
  reinterpret_cast<ushort4*>(out)[i] = o;
}

// ---------------- fused multi-tensor f32 -> bf16 ----------------
struct Segs {
  const float* src[7];
  u16* dst[7];
  int endblk[7];  // cumulative block counts
};
__global__ __launch_bounds__(256) void cvt_multi_kernel(Segs sg) {
  int b = blockIdx.x;
  int i = 0;
#pragma unroll
  for (int k = 0; k < 6; ++k) i += (b >= sg.endblk[k]);
  int start = (i == 0) ? 0 : sg.endblk[i - 1];
  int idx = (b - start) * 256 + threadIdx.x;
  float4 v = reinterpret_cast<const float4*>(sg.src[i])[idx];
  ushort4 o;
  o.x = f2bf(v.x); o.y = f2bf(v.y); o.z = f2bf(v.z); o.w = f2bf(v.w);
  reinterpret_cast<ushort4*>(sg.dst[i])[idx] = o;
}

// ---------------- bf16 transpose [B,N,C] -> [B,C,N], 64x64 tiles ----------------
__global__ __launch_bounds__(256) void transpose_kernel(const u16* __restrict__ in,
                                                        u16* __restrict__ out) {
  __shared__ u16 T[64][72];
  int n0 = blockIdx.x * 64, c0 = blockIdx.y * 64, b = blockIdx.z;
  const u16* src = in + (long)b * N_ * C_;
  u16* dst = out + (long)b * C_ * N_;
  int t = threadIdx.x;
  int r = t >> 3, cq = (t & 7) * 8;
#pragma unroll
  for (int h = 0; h < 2; ++h) {
    const u16* p = src + (long)(n0 + r + h * 32) * C_ + c0 + cq;
    ushort4 v0 = *reinterpret_cast<const ushort4*>(p);
    ushort4 v1 = *reinterpret_cast<const ushort4*>(p + 4);
    T[r + h * 32][cq + 0] = v0.x; T[r + h * 32][cq + 1] = v0.y;
    T[r + h * 32][cq + 2] = v0.z; T[r + h * 32][cq + 3] = v0.w;
    T[r + h * 32][cq + 4] = v1.x; T[r + h * 32][cq + 5] = v1.y;
    T[r + h * 32][cq + 6] = v1.z; T[r + h * 32][cq + 7] = v1.w;
  }
  __syncthreads();
  int cc = t >> 3, nq = (t & 7) * 8;
#pragma unroll
  for (int h = 0; h < 2; ++h) {
    int cl = cc + h * 32;
    ushort4 w0, w1;
    w0.x = T[nq + 0][cl]; w0.y = T[nq + 1][cl];
    w0.z = T[nq + 2][cl]; w0.w = T[nq + 3][cl];
    w1.x = T[nq + 4][cl]; w1.y = T[nq + 5][cl];
    w1.z = T[nq + 6][cl]; w1.w = T[nq + 7][cl];
    u16* q = dst + (long)(c0 + cl) * N_ + n0 + nq;
    *reinterpret_cast<ushort4*>(q) = w0;
    *reinterpret_cast<ushort4*>(q + 4) = w1;
  }
}

// ---------------- counted-vmcnt phase-split MFMA GEMM (NT) ----------------
// C[m,j] = sum_k A[m,k]*B[j,k]. BK=32, 4 LDS buffers (2-tile prefetch),
// counted vmcnt, XOR chunk swizzle, setprio, XCD swizzle, z-offset batching.
// 512 thr = 8 waves (BM/WM x BN/WN).
// EPI: 0 bf16 (bias nullable... no bias) | 1 bf16 +bias[j] | 2 bf16 gelu(v+bias[j])
template <int BM, int BN, int WM, int WN, int EPI>
__global__ __launch_bounds__(512, 2) void gemm8p(
    const u16* __restrict__ A, const u16* __restrict__ B, u16* __restrict__ C,
    const float* __restrict__ bias, int K, int lda, int ldb, int ldc,
    long sAz, long sBz, long sCz) {
  constexpr int BK = 32;
  constexpr int GA = BM / 128, GB = BN / 128, G = GA + GB;
  constexpr int FM = WM / 16, FN = WN / 16, FM0 = FM / 2;
  constexpr int NWN = BN / WN;

  __shared__ __attribute__((aligned(16))) u16 As[4][BM * BK];
  __shared__ __attribute__((aligned(16))) u16 Bs[4][BN * BK];

  A += (long)blockIdx.z * sAz;
  B += (long)blockIdx.z * sBz;
  C += (long)blockIdx.z * sCz;

  int gy = gridDim.y;
  int nwg = gridDim.x * gy;
  int id = blockIdx.x * gy + blockIdx.y;
  int nid = (id & 7) * (nwg >> 3) + (id >> 3);
  int row0 = (nid / gy) * BM, col0 = (nid % gy) * BN;

  int tid = threadIdx.x;
  int lane = tid & 63, wid = tid >> 6;
  int wr = wid / NWN, wc = wid % NWN;
  int lr = lane & 15, q = lane >> 4;

  auto stA = [&](int buf, int k0) {
#pragma unroll
    for (int g = 0; g < GA; ++g) {
      int c = g * 512 + tid;
      int r = c >> 2, ck = c & 3;
      GLD(A + (long)(row0 + r) * lda + k0 + ((ck ^ ((r >> 1) & 3)) << 3),
          &As[buf][c * 8]);
    }
  };
  auto stB = [&](int buf, int k0) {
#pragma unroll
    for (int g = 0; g < GB; ++g) {
      int c = g * 512 + tid;
      int r = c >> 2, ck = c & 3;
      GLD(B + (long)(col0 + r) * ldb + k0 + ((ck ^ ((r >> 1) & 3)) << 3),
          &Bs[buf][c * 8]);
    }
  };
  auto rd = [&](const u16* Tb, int r) {
    return *reinterpret_cast<const short8*>(&Tb[r * 32 + ((q ^ ((r >> 1) & 3)) << 3)]);
  };

  f32x4 acc[FM][FN] = {};
  int NT = K / BK;

  stA(0, 0); stB(0, 0);
  stA(1, BK); stB(1, BK);
  stA(2, 2 * BK); stB(2, 2 * BK);

  for (int t = 0; t < NT; ++t) {
    const u16* Ab = As[t & 3];
    const u16* Bb = Bs[t & 3];
    bool pf = (t + 3) < NT;
    int bn = (t + 3) & 3, kn = (t + 3) * BK;

    if constexpr (G == 4) asm volatile("s_waitcnt vmcnt(8)" ::: "memory");
    else                  asm volatile("s_waitcnt vmcnt(6)" ::: "memory");
    __builtin_amdgcn_s_barrier();

    short8 bf[FN], af[FM0];
#pragma unroll
    for (int nj = 0; nj < FN; ++nj) bf[nj] = rd(Bb, wc * WN + nj * 16 + lr);
#pragma unroll
    for (int mi = 0; mi < FM0; ++mi) af[mi] = rd(Ab, wr * WM + mi * 16 + lr);
    if (pf) stA(bn, kn);
    __builtin_amdgcn_s_barrier();
    asm volatile("s_waitcnt lgkmcnt(0)" ::: "memory");
    __builtin_amdgcn_sched_barrier(0);
    __builtin_amdgcn_s_setprio(1);
#pragma unroll
    for (int mi = 0; mi < FM0; ++mi)
#pragma unroll
      for (int nj = 0; nj < FN; ++nj)
        acc[mi][nj] = MFMA16(af[mi], bf[nj], acc[mi][nj], 0, 0, 0);
    __builtin_amdgcn_s_setprio(0);
    __builtin_amdgcn_s_barrier();
#pragma unroll
    for (int mi = 0; mi < FM - FM0; ++mi)
      af[mi] = rd(Ab, wr * WM + (FM0 + mi) * 16 + lr);
    if (pf) stB(bn, kn);
    __builtin_amdgcn_s_barrier();
    asm volatile("s_waitcnt lgkmcnt(0)" ::: "memory");
    __builtin_amdgcn_sched_barrier(0);
    __builtin_amdgcn_s_setprio(1);
#pragma unroll
    for (int mi = 0; mi < FM - FM0; ++mi)
#pragma unroll
      for (int nj = 0; nj < FN; ++nj)
        acc[FM0 + mi][nj] = MFMA16(af[mi], bf[nj], acc[FM0 + mi][nj], 0, 0, 0);
    __builtin_amdgcn_s_setprio(0);
    __builtin_amdgcn_s_barrier();
  }

  int lc = lane & 15, rb = (lane >> 4) * 4;
#pragma unroll
  for (int mi = 0; mi < FM; ++mi) {
#pragma unroll
    for (int nj = 0; nj < FN; ++nj) {
      int j = col0 + wc * WN + nj * 16 + lc;
      int m0 = row0 + wr * WM + mi * 16 + rb;
#pragma unroll
      for (int r = 0; r < 4; ++r) {
        long m = m0 + r;
        float v = acc[mi][nj][r];
        if constexpr (EPI == 0) {
          C[m * ldc + j] = f2bf(v);
        } else if constexpr (EPI == 1) {
          C[m * ldc + j] = f2bf(v + bias[j]);
        } else {  // 2: fast tanh-GELU
          float tt = v + bias[j];
          float u = tt * (0.7978845608f + 0.0356774081f * tt * tt);
          float e = __expf(2.f * u);
          float th = 1.f - 2.f / (e + 1.f);
          C[m * ldc + j] = f2bf(0.5f * tt * (1.f + th));
        }
      }
    }
  }
}

// ---------------- generic 128-tile NT MFMA GEMM (phase A) ----------------
// EPI: 7 f32 split-K partial | 10 fused Kp/Vp (z<4: Kp via B/Cout; z>=4: Vp via B2/Cout2)
template <int BM, int BN, int EPI, int SPLITK>
__global__ __launch_bounds__(256, 2) void gemm_nt(
    const u16* __restrict__ A, const u16* B, void* __restrict__ Cout,
    const float* __restrict__ bias, int K, int lda, int ldb, int ldc,
    long sA1, long sB1, long sC1, long sCh, int nz, float alpha,
    const u16* __restrict__ B2, void* __restrict__ Cout2) {
  constexpr int BK = 64;
  constexpr int WM = BM / 2, WN = BN / 2;
  constexpr int FM = WM / 16, FN = WN / 16;
  constexpr int CA = BM / 32, CB = BN / 32;

  __shared__ __attribute__((aligned(16))) u16 As[BM * BK];
  __shared__ __attribute__((aligned(16))) u16 Bs[BN * BK];

  int z, chunk, kv = 0;
  long coff;
  if constexpr (EPI == 10) {
    z = blockIdx.z; chunk = 0;
    kv = z >> 2;
    int zbq = z & 3;
    A += (long)zbq * 131072;
    if (kv) B = B2;
    coff = (long)zbq * 131072;
  } else {
    if constexpr (SPLITK > 1) { z = blockIdx.z % nz; chunk = blockIdx.z / nz; }
    else { z = blockIdx.z; chunk = 0; }
    A += (long)z * 0;  // (phase-A callers fold offsets via sA1/sB1)
    A += (long)z * sA1;
    B += (long)z * sB1;
    coff = (long)z * sC1 + (long)chunk * sCh;
  }

  int tid = threadIdx.x;
  int lane = tid & 63, wid = tid >> 6;
  int wr = wid >> 1, wc = wid & 1;
  int row0 = blockIdx.x * BM, col0 = blockIdx.y * BN;

  int Kc = K / SPLITK;
  int kbeg = chunk * Kc;

  f32x4 acc[FM][FN] = {};

  for (int k0 = kbeg; k0 < kbeg + Kc; k0 += BK) {
#pragma unroll
    for (int i = 0; i < CA; ++i) {
      int c = tid + i * 256;
      GLD(A + (long)(row0 + (c >> 3)) * lda + k0 + (c & 7) * 8, As + c * 8);
    }
#pragma unroll
    for (int i = 0; i < CB; ++i) {
      int c = tid + i * 256;
      GLD(B + (long)(col0 + (c >> 3)) * ldb + k0 + (c & 7) * 8, Bs + c * 8);
    }
    __syncthreads();

    int lr = lane & 15, lk = (lane >> 4) * 8;
#pragma unroll
    for (int kk = 0; kk < BK; kk += 32) {
      short8 af[FM], bfr[FN];
#pragma unroll
      for (int mi = 0; mi < FM; ++mi)
        af[mi] = *reinterpret_cast<const short8*>(&As[(wr * WM + mi * 16 + lr) * BK + kk + lk]);
#pragma unroll
      for (int nj = 0; nj < FN; ++nj)
        bfr[nj] = *reinterpret_cast<const short8*>(&Bs[(wc * WN + nj * 16 + lr) * BK + kk + lk]);
#pragma unroll
      for (int mi = 0; mi < FM; ++mi)
#pragma unroll
        for (int nj = 0; nj < FN; ++nj)
          acc[mi][nj] = MFMA16(af[mi], bfr[nj], acc[mi][nj], 0, 0, 0);
    }
    __syncthreads();
  }

  int lc = lane & 15, rb = (lane >> 4) * 4;
#pragma unroll
  for (int mi = 0; mi < FM; ++mi) {
#pragma unroll
    for (int nj = 0; nj < FN; ++nj) {
      int j = col0 + wc * WN + nj * 16 + lc;
      int m0 = row0 + wr * WM + mi * 16 + rb;
#pragma unroll
      for (int r = 0; r < 4; ++r) {
        int m = m0 + r;
        float v = acc[mi][nj][r];
        if constexpr (EPI == 10) {
          if (kv == 0)
            reinterpret_cast<u16*>(Cout)[coff + (long)m * 512 + j] = f2bf(v + bias[m]);
          else
            reinterpret_cast<u16*>(Cout2)[coff + (long)j * 256 + m] = f2bf(v + bias[m]);
        } else {  // 7: f32 split-K partial
          reinterpret_cast<float*>(Cout)[coff + (long)m * ldc + j] = v;
        }
      }
    }
  }
}

// ---------------- split-K reduce: sum 8 f32 chunks -> bf16 ----------------
__global__ __launch_bounds__(256) void reduce8_kernel(const float* __restrict__ part,
                                                      u16* __restrict__ out) {
  int i = blockIdx.x * 256 + threadIdx.x;
  const float4* p = reinterpret_cast<const float4*>(part);
  float4 s = p[i];
#pragma unroll
  for (int c = 1; c < 8; ++c) {
    float4 t = p[i + c * 131072];
    s.x += t.x; s.y += t.y; s.z += t.z; s.w += t.w;
  }
  ushort4 o;
  o.x = f2bf(s.x); o.y = f2bf(s.y); o.z = f2bf(s.z); o.w = f2bf(s.w);
  reinterpret_cast<ushort4*>(out)[i] = o;
}

// ---------------- fused attention: S=Q.Kp^T, softmax, O=P.Vp ----------------
__global__ __launch_bounds__(512, 2) void attn_kernel(
    const u16* __restrict__ Q, const u16* __restrict__ Kp,
    const u16* __restrict__ Vpt, u16* __restrict__ O) {
  constexpr int LQ = 72, LKP = 72, LVP = 264, LP = 264;
  __shared__ __attribute__((aligned(16))) u16 Q_s[128 * LQ];
  __shared__ __attribute__((aligned(16))) u16 Kp_s[256 * LKP];
  __shared__ __attribute__((aligned(16))) u16 Vp_s[64 * LVP];
  __shared__ __attribute__((aligned(16))) u16 P_s[128 * LP];

  int n0 = blockIdx.x * 128;
  int bh = blockIdx.y;
  int b = bh >> 3, h = bh & 7;
  long qbase = ((long)b * N_ + n0) * 512 + h * 64;
  const u16* Kpb = Kp + ((long)b * KD_) * 512 + h * 64;
  const u16* Vpb = Vpt + ((long)b * 512 + h * 64) * KD_;

  int tid = threadIdx.x;
#pragma unroll
  for (int i = 0; i < 2; ++i) {
    int c = tid + i * 512;
    int r = c >> 3, c8 = (c & 7) * 8;
    *reinterpret_cast<uint4*>(&Q_s[r * LQ + c8]) =
        *reinterpret_cast<const uint4*>(Q + qbase + (long)r * 512 + c8);
  }
#pragma unroll
  for (int i = 0; i < 4; ++i) {
    int c = tid + i * 512;
    int r = c >> 3, c8 = (c & 7) * 8;
    *reinterpret_cast<uint4*>(&Kp_s[r * LKP + c8]) =
        *reinterpret_cast<const uint4*>(Kpb + (long)r * 512 + c8);
  }
#pragma unroll
  for (int i = 0; i < 4; ++i) {
    int c = tid + i * 512;
    int r = c >> 5, c8 = (c & 31) * 8;
    *reinterpret_cast<uint4*>(&Vp_s[r * LVP + c8]) =
        *reinterpret_cast<const uint4*>(Vpb + (long)r * KD_ + c8);
  }
  __syncthreads();

  int lane = tid & 63, w = tid >> 6;
  int q0 = w * 16;
  int lr = lane & 15, lk = (lane >> 4) * 8;
  int lc = lane & 15, rb = (lane >> 4) * 4;

  f32x4 acc[16] = {};
  short8 af0 = *reinterpret_cast<const short8*>(&Q_s[(q0 + lr) * LQ + lk]);
  short8 af1 = *reinterpret_cast<const short8*>(&Q_s[(q0 + lr) * LQ + 32 + lk]);
#pragma unroll
  for (int t = 0; t < 16; ++t) {
    short8 b0 = *reinterpret_cast<const short8*>(&Kp_s[(t * 16 + lr) * LKP + lk]);
    short8 b1 = *reinterpret_cast<const short8*>(&Kp_s[(t * 16 + lr) * LKP + 32 + lk]);
    acc[t] = MFMA16(af0, b0, acc[t], 0, 0, 0);
    acc[t] = MFMA16(af1, b1, acc[t], 0, 0, 0);
  }

  float mx[4] = {-3.4e38f, -3.4e38f, -3.4e38f, -3.4e38f};
#pragma unroll
  for (int t = 0; t < 16; ++t)
#pragma unroll
    for (int r = 0; r < 4; ++r) {
      acc[t][r] *= 0.125f;
      mx[r] = fmaxf(mx[r], acc[t][r]);
    }
#pragma unroll
  for (int o = 1; o < 16; o <<= 1)
#pragma unroll
    for (int r = 0; r < 4; ++r) mx[r] = fmaxf(mx[r], __shfl_xor(mx[r], o));
  float sm[4] = {0.f, 0.f, 0.f, 0.f};
#pragma unroll
  for (int t = 0; t < 16; ++t)
#pragma unroll
    for (int r = 0; r < 4; ++r) {
      float e = __expf(acc[t][r] - mx[r]);
      acc[t][r] = e;
      sm[r] += e;
    }
#pragma unroll
  for (int o = 1; o < 16; o <<= 1)
#pragma unroll
    for (int r = 0; r < 4; ++r) sm[r] += __shfl_xor(sm[r], o);
  float inv[4];
#pragma unroll
  for (int r = 0; r < 4; ++r) inv[r] = 1.f / sm[r];
#pragma unroll
  for (int t = 0; t < 16; ++t)
#pragma unroll
    for (int r = 0; r < 4; ++r)
      P_s[(q0 + rb + r) * LP + t * 16 + lc] = f2bf(acc[t][r] * inv[r]);

  f32x4 o2[4] = {};
#pragma unroll
  for (int kk = 0; kk < 8; ++kk) {
    short8 pa = *reinterpret_cast<const short8*>(&P_s[(q0 + lr) * LP + kk * 32 + lk]);
#pragma unroll
    for (int nj = 0; nj < 4; ++nj) {
      short8 vb = *reinterpret_cast<const short8*>(&Vp_s[(nj * 16 + lr) * LVP + kk * 32 + lk]);
      o2[nj] = MFMA16(pa, vb, o2[nj], 0, 0, 0);
    }
  }
#pragma unroll
  for (int nj = 0; nj < 4; ++nj)
#pragma unroll
    for (int r = 0; r < 4; ++r)
      O[qbase + (long)(q0 + rb + r) * 512 + nj * 16 + lc] = f2bf(o2[nj][r]);
}

// ---------------- residual add + LayerNorm (row of 512) ----------------
// y = yin (+ yin2) (+ bias2); x = xin32 or xinb; out = LN(x+y)
__global__ __launch_bounds__(256) void add_ln_kernel(
    const float* __restrict__ xin32, const u16* __restrict__ xinb,
    const u16* __restrict__ yin, const u16* __restrict__ yin2,
    const float* __restrict__ bias2, const float* __restrict__ g,
    const float* __restrict__ bt, float* __restrict__ xout32,
    u16* __restrict__ xbout) {
  int row = blockIdx.x * 4 + (threadIdx.x >> 6);
  int lane = threadIdx.x & 63;
  int c0 = lane * 8;
  long base = (long)row * C_ + c0;
  float s[8];
  if (xin32) {
    float4 a0 = *reinterpret_cast<const float4*>(xin32 + base);
    float4 a1 = *reinterpret_cast<const float4*>(xin32 + base + 4);
    s[0] = a0.x; s[1] = a0.y; s[2] = a0.z; s[3] = a0.w;
    s[4] = a1.x; s[5] = a1.y; s[6] = a1.z; s[7] = a1.w;
  } else {
    ushort4 x0 = *reinterpret_cast<const ushort4*>(xinb + base);
    ushort4 x1 = *reinterpret_cast<const ushort4*>(xinb + base + 4);
    s[0] = bf2f(x0.x); s[1] = bf2f(x0.y); s[2] = bf2f(x0.z); s[3] = bf2f(x0.w);
    s[4] = bf2f(x1.x); s[5] = bf2f(x1.y); s[6] = bf2f(x1.z); s[7] = bf2f(x1.w);
  }
  ushort4 u0 = *reinterpret_cast<const ushort4*>(yin + base);
  ushort4 u1 = *reinterpret_cast<const ushort4*>(yin + base + 4);
  s[0] += bf2f(u0.x); s[1] += bf2f(u0.y); s[2] += bf2f(u0.z); s[3] += bf2f(u0.w);
  s[4] += bf2f(u1.x); s[5] += bf2f(u1.y); s[6] += bf2f(u1.z); s[7] += bf2f(u1.w);
  if (yin2) {
    ushort4 v0 = *reinterpret_cast<const ushort4*>(yin2 + base);
    ushort4 v1 = *reinterpret_cast<const ushort4*>(yin2 + base + 4);
    s[0] += bf2f(v0.x); s[1] += bf2f(v0.y); s[2] += bf2f(v0.z); s[3] += bf2f(v0.w);
    s[4] += bf2f(v1.x); s[5] += bf2f(v1.y); s[6] += bf2f(v1.z); s[7] += bf2f(v1.w);
  }
  if (bias2) {
#pragma unroll
    for (int i = 0; i < 8; ++i) s[i] += bias2[c0 + i];
  }
  float sum = 0.f;
#pragma unroll
  for (int i = 0; i < 8; ++i) sum += s[i];
#pragma unroll
  for (int o = 1; o < 64; o <<= 1) sum += __shfl_xor(sum, o);
  float mean = sum * (1.f / C_);
  float var = 0.f;
#pragma unroll
  for (int i = 0; i < 8; ++i) { float d = s[i] - mean; var += d * d; }
#pragma unroll
  for (int o = 1; o < 64; o <<= 1) var += __shfl_xor(var, o);
  float inv = rsqrtf(var * (1.f / C_) + 1e-5f);
  float o[8];
#pragma unroll
  for (int i = 0; i < 8; ++i) o[i] = (s[i] - mean) * inv * g[c0 + i] + bt[c0 + i];
  if (xout32) {
    float4 f0 = {o[0], o[1], o[2], o[3]};
    float4 f1 = {o[4], o[5], o[6], o[7]};
    *reinterpret_cast<float4*>(xout32 + base) = f0;
    *reinterpret_cast<float4*>(xout32 + base + 4) = f1;
  }
  if (xbout) {
    ushort4 w0 = {f2bf(o[0]), f2bf(o[1]), f2bf(o[2]), f2bf(o[3])};
    ushort4 w1 = {f2bf(o[4]), f2bf(o[5]), f2bf(o[6]), f2bf(o[7])};
    *reinterpret_cast<ushort4*>(xbout + base) = w0;
    *reinterpret_cast<ushort4*>(xbout + base + 4) = w1;
  }
}

extern "C" void kernel_launch(void* const* d_in, const int* in_sizes, int n_in,
                              void* d_out, int out_size, void* d_ws, size_t ws_size,
                              hipStream_t stream) {
  const float* x    = (const float*)d_in[0];
  const float* Wq   = (const float*)d_in[1];
  const float* Wk   = (const float*)d_in[2];
  const float* Wv   = (const float*)d_in[3];
  const float* Wo   = (const float*)d_in[4];
  const float* bo   = (const float*)d_in[5];
  const float* ln1g = (const float*)d_in[6];
  const float* ln1b = (const float*)d_in[7];
  const float* W1   = (const float*)d_in[8];
  const float* b1   = (const float*)d_in[9];
  const float* W2   = (const float*)d_in[10];
  const float* b2   = (const float*)d_in[11];
  const float* ln2g = (const float*)d_in[12];
  const float* ln2b = (const float*)d_in[13];
  const float* Ew   = (const float*)d_in[14];
  const float* Eb   = (const float*)d_in[15];
  float* xc = (float*)d_out;  // final f32 output only

  char* wsp = (char*)d_ws;
  size_t off = 0;
  auto alloc = [&](size_t bytes) -> void* {
    void* p = wsp + off;
    off = (off + bytes + 255) & ~(size_t)255;
    return p;
  };
  u16* xb  = (u16*)alloc(8388608UL * 2);    // x bf16 [B,N,C]
  u16* BIG = (u16*)alloc(33554432UL * 2);   // 64MB: xT+xE-partials | h1 [16384,2048]
  u16* Qb  = (u16*)alloc(8388608UL * 2);    // Q; attn-out in place
  u16* yb  = (u16*)alloc(8388608UL * 2);    // y bf16 (attn path)
  u16* Pp  = (u16*)alloc(16777216UL * 2);   // W2 partials p0,p1 [16384,512] each
  u16* xEb = (u16*)alloc(524288UL * 2);
  u16* Kpb = (u16*)alloc(524288UL * 2);
  u16* Vpt = (u16*)alloc(524288UL * 2);
  u16* wqb = (u16*)alloc(524288UL * 2);
  u16* wkb = (u16*)alloc(524288UL * 2);
  u16* wvb = (u16*)alloc(524288UL * 2);
  u16* wob = (u16*)alloc(524288UL * 2);
  u16* w1b = (u16*)alloc(2097152UL * 2);
  u16* w2b = (u16*)alloc(2097152UL * 2);
  u16* ewb = (u16*)alloc(1048576UL * 2);
  (void)ws_size; (void)in_sizes; (void)n_in; (void)out_size;

  // x convert (biggest, own launch)
  cvt_kernel<<<dim3(8192), dim3(256), 0, stream>>>(x, xb, 2097152);
  // fused weight converts: Wq,Wk,Wv,Wo (512 blk each), W1,W2 (2048), Ew (1024)
  Segs sg;
  sg.src[0] = Wq; sg.dst[0] = wqb;
  sg.src[1] = Wk; sg.dst[1] = wkb;
  sg.src[2] = Wv; sg.dst[2] = wvb;
  sg.src[3] = Wo; sg.dst[3] = wob;
  sg.src[4] = W1; sg.dst[4] = w1b;
  sg.src[5] = W2; sg.dst[5] = w2b;
  sg.src[6] = Ew; sg.dst[6] = ewb;
  sg.endblk[0] = 512;  sg.endblk[1] = 1024; sg.endblk[2] = 1536;
  sg.endblk[3] = 2048; sg.endblk[4] = 4096; sg.endblk[5] = 6144;
  sg.endblk[6] = 7168;
  cvt_multi_kernel<<<dim3(7168), dim3(256), 0, stream>>>(sg);

  for (int l = 0; l < L_; ++l) {
    const u16* wq = wqb + (long)l * 262144;
    const u16* wk = wkb + (long)l * 262144;
    const u16* wv = wvb + (long)l * 262144;
    const u16* wo = wob + (long)l * 262144;
    const u16* w1 = w1b + (long)l * 1048576;
    const u16* w2 = w2b + (long)l * 1048576;

    // ---- phase A: shared E-projection ----
    u16* xT = BIG;                           // [B,C,N] 16MB
    float* partF = (float*)(BIG + 8388608);  // 16MB f32
    transpose_kernel<<<dim3(64, 8, 4), dim3(256), 0, stream>>>(xb, xT);
    gemm_nt<128, 128, 7, 8><<<dim3(2, 4, 32), dim3(256), 0, stream>>>(
        ewb, xT, partF, nullptr, 4096, 4096, 4096, 512,
        0, 2097152, 131072, 524288, 4, 1.f, nullptr, nullptr);
    reduce8_kernel<<<dim3(512), dim3(256), 0, stream>>>(partF, xEb);
    // fused Kp (z<4) + Vp (z>=4)
    gemm_nt<128, 128, 10, 1><<<dim3(2, 4, 8), dim3(256), 0, stream>>>(
        xEb, wk, Kpb, Eb, 512, 512, 512, 512,
        0, 0, 0, 0, 8, 1.f, wv, Vpt);
    // Q = x @ Wq^T  (BM=128 BN=256, grid 256)
    gemm8p<128, 256, 64, 64, 0><<<dim3(128, 2), dim3(512), 0, stream>>>(
        xb, wq, Qb, nullptr, 512, 512, 512, 512, 0, 0, 0);

    // ---- phase B: fused attention ----
    attn_kernel<<<dim3(32, 32), dim3(512), 0, stream>>>(Qb, Kpb, Vpt, Qb);

    // y = o @ Wo^T + bo
    gemm8p<128, 256, 64, 64, 1><<<dim3(128, 2), dim3(512), 0, stream>>>(
        Qb, wo, yb, bo + (long)l * 512, 512, 512, 512, 512, 0, 0, 0);
    add_ln_kernel<<<dim3(4096), dim3(256), 0, stream>>>(
        l == 0 ? x : nullptr, l == 0 ? nullptr : xb, yb, nullptr, nullptr,
        ln1g + (long)l * 512, ln1b + (long)l * 512, nullptr, xb);

    // ---- phase C: FFN ----
    u16* h1 = BIG;  // [16384, 2048] 64MB
    gemm8p<256, 256, 128, 64, 2><<<dim3(64, 8), dim3(512), 0, stream>>>(
        xb, w1, h1, b1 + (long)l * 2048, 512, 512, 512, 2048, 0, 0, 0);
    // W2: z = FF-half -> bf16 partials p0, p1 (no bias)
    gemm8p<256, 256, 128, 64, 0><<<dim3(64, 2, 2), dim3(512), 0, stream>>>(
        h1, w2, Pp, nullptr, 1024, 2048, 2048, 512, 1024, 1024, 8388608);
    // x = LN(x + p0 + p1 + b2)
    add_ln_kernel<<<dim3(4096), dim3(256), 0, stream>>>(
        nullptr, xb, Pp, Pp + 8388608, b2 + (long)l * 512,
        ln2g + (long)l * 512, ln2b + (long)l * 512,
        (l == L_ - 1) ? xc : nullptr, (l == L_ - 1) ? (u16*)nullptr : xb);
  }
}